// Round 15
// baseline (960.297 us; speedup 1.0000x reference)
//
#include <hip/hip_runtime.h>
#include <hip/hip_bf16.h>

// Problem constants
#define T_STEPS 64
#define BATCH   32
#define HID     1024
#define VOCAB   32000
#define WLEN_   101
#define WSZ_    50
#define SENC    229
#define LBLK    64      // blocks per LSTM role; grid = 3*LBLK = 192

static const size_t Y_SZ   = (size_t)T_STEPS * BATCH * VOCAB;   // 65,536,000
static const size_t HN_SZ  = (size_t)2 * BATCH * HID;           // 65,536
static const size_t CTX_OFF = Y_SZ + 2 * HN_SZ;                 // y + h_n + c_n

typedef __attribute__((ext_vector_type(8)))  unsigned short us8;
typedef __attribute__((ext_vector_type(8)))  __bf16 bf16x8;
typedef __attribute__((ext_vector_type(4)))  float f32x4;
typedef __attribute__((ext_vector_type(16))) float f32x16;

static __device__ inline unsigned short f2bf(float x) {
    __hip_bfloat16 b = __float2bfloat16(x);
    return __builtin_bit_cast(unsigned short, b);
}

// Coherence-point (LLC) accesses for the LSTM cross-block exchange.
#define GLD_US8_SC(dst, ptr) \
    asm volatile("global_load_dwordx4 %0, %1, off sc0 sc1" : "=v"(dst) : "v"(ptr) : "memory")
#define GLD_F32_SC(dst, ptr) \
    asm volatile("global_load_dword %0, %1, off sc0 sc1" : "=v"(dst) : "v"(ptr) : "memory")
#define GST_U16_SC(ptr, val) \
    asm volatile("global_store_short %0, %1, off sc0 sc1" :: "v"(ptr), "v"(val) : "memory")
#define GST_U32_SC(ptr, val) \
    asm volatile("global_store_dword %0, %1, off sc0 sc1" :: "v"(ptr), "v"(val) : "memory")
#define WAIT_VM0() asm volatile("s_waitcnt vmcnt(0)" ::: "memory")

// ---------------------------------------------------------------------------
// fp32 GEMM (attn-proj path only — keeps window indices exact)
// ---------------------------------------------------------------------------
__global__ __launch_bounds__(256) void gemm_bt(
    const float* __restrict__ A, const float* __restrict__ W,
    const float* __restrict__ b1, const float* __restrict__ b2,
    float* __restrict__ out, int M, int N, int K, int act)
{
    __shared__ __align__(16) float As[16 * 132];
    __shared__ __align__(16) float Ws[16 * 68];
    const int tid  = threadIdx.x;
    const int col0 = blockIdx.x * 64;
    const int row0 = blockIdx.y * 128;
    const int ty   = tid >> 4;
    const int tx   = tid & 15;

    float acc[8][4];
#pragma unroll
    for (int i = 0; i < 8; ++i)
#pragma unroll
        for (int j = 0; j < 4; ++j) acc[i][j] = 0.f;

    for (int k0 = 0; k0 < K; k0 += 16) {
#pragma unroll
        for (int li = 0; li < 2; ++li) {
            int f  = tid + li * 256;
            int r  = f >> 2;
            int kq = (f & 3) << 2;
            float4 v = *reinterpret_cast<const float4*>(A + (size_t)(row0 + r) * K + k0 + kq);
            As[(kq + 0) * 132 + r] = v.x;
            As[(kq + 1) * 132 + r] = v.y;
            As[(kq + 2) * 132 + r] = v.z;
            As[(kq + 3) * 132 + r] = v.w;
        }
        {
            int n  = tid >> 2;
            int kq = (tid & 3) << 2;
            float4 v = *reinterpret_cast<const float4*>(W + (size_t)(col0 + n) * K + k0 + kq);
            Ws[(kq + 0) * 68 + n] = v.x;
            Ws[(kq + 1) * 68 + n] = v.y;
            Ws[(kq + 2) * 68 + n] = v.z;
            Ws[(kq + 3) * 68 + n] = v.w;
        }
        __syncthreads();
#pragma unroll
        for (int k = 0; k < 16; ++k) {
            const float4 a0 = *reinterpret_cast<const float4*>(&As[k * 132 + ty * 8]);
            const float4 a1 = *reinterpret_cast<const float4*>(&As[k * 132 + ty * 8 + 4]);
            const float4 b0 = *reinterpret_cast<const float4*>(&Ws[k * 68 + tx * 4]);
            float av[8] = {a0.x, a0.y, a0.z, a0.w, a1.x, a1.y, a1.z, a1.w};
            float bv[4] = {b0.x, b0.y, b0.z, b0.w};
#pragma unroll
            for (int i = 0; i < 8; ++i)
#pragma unroll
                for (int j = 0; j < 4; ++j) acc[i][j] = fmaf(av[i], bv[j], acc[i][j]);
        }
        __syncthreads();
    }

#pragma unroll
    for (int j = 0; j < 4; ++j) {
        int n = col0 + tx * 4 + j;
        float bias = 0.f;
        if (b1) bias += b1[n];
        if (b2) bias += b2[n];
#pragma unroll
        for (int i = 0; i < 8; ++i) {
            float v = acc[i][j] + bias;
            if (act == 1) v = fmaxf(v, 0.f);
            else if (act == 2) v = tanhf(v);
            out[(size_t)(row0 + ty * 8 + i) * N + n] = v;
        }
    }
}

// ---------------------------------------------------------------------------
// bf16 MFMA GEMM, m97-style (verified rounds 8-14). ntout: stream fp32 out.
// ---------------------------------------------------------------------------
__global__ __launch_bounds__(256) void gemm_lds_bt(
    const unsigned short* __restrict__ A, const unsigned short* __restrict__ W,
    const float* __restrict__ b1, const float* __restrict__ b2,
    float* __restrict__ out, unsigned short* __restrict__ out_bf,
    int M, int N, int K, int relu, int ntout)
{
    __shared__ __align__(16) unsigned short As[8192];
    __shared__ __align__(16) unsigned short Ws[8192];
    const int tid  = threadIdx.x;
    const int lane = tid & 63;
    const int wave = tid >> 6;

    const int nwg = gridDim.x;
    const int bid = blockIdx.x;
    const int q = nwg >> 3, r8 = nwg & 7;
    const int xcd = bid & 7, sidx = bid >> 3;
    const int wgid = (xcd < r8 ? xcd * (q + 1) : r8 * (q + 1) + (xcd - r8) * q) + sidx;
    const int mt = M >> 7;
    const int row0 = (wgid % mt) << 7;
    const int col0 = (wgid / mt) << 7;

    const int m0   = (wave >> 1) * 64;
    const int n0   = (wave & 1) * 64;
    const int lrow = lane & 15;
    const int kc   = lane >> 4;

    f32x4 acc[4][4];
#pragma unroll
    for (int i = 0; i < 4; ++i)
#pragma unroll
        for (int j = 0; j < 4; ++j) acc[i][j] = (f32x4){0.f, 0.f, 0.f, 0.f};

    const bool isA = (wave < 2);
    const int  lw  = wave & 1;
    const unsigned short* gbase = isA ? (A + (size_t)row0 * K) : (W + (size_t)col0 * K);
    unsigned short* lbase = isA ? As : Ws;

    for (int k0 = 0; k0 < K; k0 += 64) {
#pragma unroll
        for (int i = 0; i < 8; ++i) {
            const int c    = lw * 512 + i * 64 + lane;
            const int row  = c >> 3;
            const int slot = c & 7;
            const unsigned short* src =
                gbase + (size_t)row * K + k0 + ((slot ^ (row & 7)) << 3);
            __builtin_amdgcn_global_load_lds(
                (const __attribute__((address_space(1))) void*)src,
                (__attribute__((address_space(3))) void*)(lbase + (size_t)(lw * 512 + i * 64) * 8),
                16, 0, 0);
        }
        __syncthreads();
#pragma unroll
        for (int ss = 0; ss < 2; ++ss) {
            us8 a[4], b[4];
#pragma unroll
            for (int f = 0; f < 4; ++f) {
                const int ar = m0 + f * 16 + lrow;
                const int as = (ss * 4 + kc) ^ (ar & 7);
                a[f] = *reinterpret_cast<const us8*>(&As[(ar * 8 + as) * 8]);
                const int br = n0 + f * 16 + lrow;
                const int bs = (ss * 4 + kc) ^ (br & 7);
                b[f] = *reinterpret_cast<const us8*>(&Ws[(br * 8 + bs) * 8]);
            }
#pragma unroll
            for (int fi = 0; fi < 4; ++fi)
#pragma unroll
                for (int fj = 0; fj < 4; ++fj)
                    acc[fi][fj] = __builtin_amdgcn_mfma_f32_16x16x32_bf16(
                        __builtin_bit_cast(bf16x8, a[fi]),
                        __builtin_bit_cast(bf16x8, b[fj]),
                        acc[fi][fj], 0, 0, 0);
        }
        __syncthreads();
    }

#pragma unroll
    for (int fi = 0; fi < 4; ++fi)
#pragma unroll
        for (int fj = 0; fj < 4; ++fj) {
            const int cN = col0 + n0 + fj * 16 + lrow;
            float bv = 0.f;
            if (b1) bv += b1[cN];
            if (b2) bv += b2[cN];
#pragma unroll
            for (int j = 0; j < 4; ++j) {
                const int r = row0 + m0 + fi * 16 + (lane >> 4) * 4 + j;
                float v = acc[fi][fj][j] + bv;
                if (relu) v = fmaxf(v, 0.f);
                if (out) {
                    if (ntout) __builtin_nontemporal_store(v, &out[(size_t)r * N + cN]);
                    else       out[(size_t)r * N + cN] = v;
                }
                if (out_bf) out_bf[(size_t)r * N + cN] = f2bf(v);
            }
        }
}

// ---------------------------------------------------------------------------
// Fused prep: Wih0->bf16, fc1w->bf16, embed+concat->bf16, fc2w->bf16 (if
// cvtfc2), zero flags. Grid 7585 x 256; all branches independent, BW-parallel.
// ---------------------------------------------------------------------------
__global__ void prep_kernel(const float* __restrict__ Wih0, unsigned short* __restrict__ Wih0_bf,
                            const float* __restrict__ fc1w, unsigned short* __restrict__ fc1w_bf,
                            const float* __restrict__ emb, const float* __restrict__ ctxin,
                            const int* __restrict__ tw, unsigned short* __restrict__ x_bf,
                            const float* __restrict__ fc2w, unsigned short* __restrict__ fc2w_bf,
                            int cvtfc2, int* __restrict__ flags)
{
    const int bid = blockIdx.x, tid = threadIdx.x;
    if (bid < 2048) {
#pragma unroll
        for (int k = 0; k < 2; ++k) {
            int i = bid * 256 + tid + k * 524288;
            float4 v0 = *reinterpret_cast<const float4*>(Wih0 + (size_t)i * 8);
            float4 v1 = *reinterpret_cast<const float4*>(Wih0 + (size_t)i * 8 + 4);
            us8 c = {f2bf(v0.x), f2bf(v0.y), f2bf(v0.z), f2bf(v0.w),
                     f2bf(v1.x), f2bf(v1.y), f2bf(v1.z), f2bf(v1.w)};
            *reinterpret_cast<us8*>(Wih0_bf + (size_t)i * 8) = c;
        }
    } else if (bid < 3072) {
        int i = (bid - 2048) * 256 + tid;
        float4 v0 = *reinterpret_cast<const float4*>(fc1w + (size_t)i * 8);
        float4 v1 = *reinterpret_cast<const float4*>(fc1w + (size_t)i * 8 + 4);
        us8 c = {f2bf(v0.x), f2bf(v0.y), f2bf(v0.z), f2bf(v0.w),
                 f2bf(v1.x), f2bf(v1.y), f2bf(v1.z), f2bf(v1.w)};
        *reinterpret_cast<us8*>(fc1w_bf + (size_t)i * 8) = c;
    } else if (bid < 3584) {
#pragma unroll
        for (int k = 0; k < 4; ++k) {
            int idx = (bid - 3072) * 256 + tid + k * 131072;
            int row = idx >> 8;
            int c8  = idx & 255;
            const float* src = (c8 < 128)
                ? emb + (size_t)tw[row] * HID + c8 * 8
                : ctxin + (size_t)row * HID + (c8 - 128) * 8;
            float4 v0 = *reinterpret_cast<const float4*>(src);
            float4 v1 = *reinterpret_cast<const float4*>(src + 4);
            us8 c = {f2bf(v0.x), f2bf(v0.y), f2bf(v0.z), f2bf(v0.w),
                     f2bf(v1.x), f2bf(v1.y), f2bf(v1.z), f2bf(v1.w)};
            *reinterpret_cast<us8*>(x_bf + (size_t)idx * 8) = c;
        }
    } else if (bid < 7584) {
        if (cvtfc2) {
            const int cidx = bid - 3584;                 // 0..3999
#pragma unroll
            for (int k = 0; k < 4; ++k) {
                int i = cidx * 1024 + k * 256 + tid;     // 4,096,000 chunks total
                float4 v0 = *reinterpret_cast<const float4*>(fc2w + (size_t)i * 8);
                float4 v1 = *reinterpret_cast<const float4*>(fc2w + (size_t)i * 8 + 4);
                us8 c = {f2bf(v0.x), f2bf(v0.y), f2bf(v0.z), f2bf(v0.w),
                         f2bf(v1.x), f2bf(v1.y), f2bf(v1.z), f2bf(v1.w)};
                *reinterpret_cast<us8*>(fc2w_bf + (size_t)i * 8) = c;
            }
        }
    } else {
        for (int i = tid; i < 6400; i += 256) flags[i] = 0;
    }
}

// ---------------------------------------------------------------------------
// 1-hop scoped barrier: block polls exactly the 64 flags it depends on.
// flags[bid*32] = (last finished phase)+2; init 1 (posted after state init).
// target==1 is the INIT barrier and MUST be polled (round-12 lesson).
// ---------------------------------------------------------------------------
static __device__ inline void poll_group(int* __restrict__ flags, int gbase, int target)
{
    if (target <= 0) return;
    const int lane = threadIdx.x & 63;
    int* fp = &flags[(gbase + lane) * 32];
    for (;;) {
        int f = __hip_atomic_load(fp, __ATOMIC_RELAXED, __HIP_MEMORY_SCOPE_AGENT);
        if (__all(f >= target)) break;
        __builtin_amdgcn_s_sleep(1);
    }
}

// ---------------------------------------------------------------------------
// 3-role fused persistent LSTM (structure verified rounds 13-14).
// This round: foldcvt removed — phase work is now uniform across blocks
// (tests the straggler-amplification theory for the 5.7us phase).
// ---------------------------------------------------------------------------
__global__ __launch_bounds__(256) void lstm_fused3(
    const float* __restrict__ gpre0,
    const float* __restrict__ Whh0, const float* __restrict__ Wih1,
    const float* __restrict__ Whh1,
    const float* __restrict__ bih1, const float* __restrict__ bhh1,
    const float* __restrict__ h0all, const float* __restrict__ c0all,
    float* __restrict__ y1o,
    unsigned short* __restrict__ fin_bf,
    float* __restrict__ hn, float* __restrict__ cn,
    unsigned short* __restrict__ hbf,
    float* __restrict__ part,
    int* __restrict__ flags)
{
    __shared__ __align__(16) us8 WB[8192];   // 128 KB
    __shared__ float red2[32 * 132];
    __shared__ float csh[512];

    const int tid  = threadIdx.x;
    const int lane = tid & 63;
    const int w    = tid >> 6;
    const int n    = lane & 31;
    const int kh   = lane >> 5;
    const int bid  = blockIdx.x;
    const int role = bid >> 6;        // 0=A, 1=C, 2=B
    const int lb   = bid & 63;
    const int j0   = lb * 16;
    const int b    = tid >> 3;
    const int jj   = tid & 7;

    unsigned short* hb0 = hbf;            // 4 x 32768
    unsigned short* hb1 = hbf + 131072;   // 2 x 32768

    {
        const float* Wsrc = (role == 0) ? Whh0 : (role == 1 ? Wih1 : Whh1);
        const int g = n >> 3, cj = n & 7;
#pragma unroll
        for (int T = 0; T < 2; ++T) {
            const float* wrow = Wsrc + (size_t)(g * HID + j0 + T * 8 + cj) * HID;
#pragma unroll
            for (int f = 0; f < 16; ++f) {
                int k = w * 256 + f * 16 + kh * 8;
                float4 v0 = *reinterpret_cast<const float4*>(wrow + k);
                float4 v1 = *reinterpret_cast<const float4*>(wrow + k + 4);
                WB[((T * 4 + w) * 16 + f) * 64 + lane] =
                    (us8){f2bf(v0.x), f2bf(v0.y), f2bf(v0.z), f2bf(v0.w),
                          f2bf(v1.x), f2bf(v1.y), f2bf(v1.z), f2bf(v1.w)};
            }
        }
    }

    float gp[2][4] = {};
    float bb[2][4] = {};
    if (role == 0) {
#pragma unroll
        for (int T = 0; T < 2; ++T) {
            csh[T * 256 + tid] = c0all[b * HID + j0 + T * 8 + jj];
#pragma unroll
            for (int g = 0; g < 4; ++g)
                gp[T][g] = gpre0[(size_t)b * 4096 + g * HID + j0 + T * 8 + jj];
        }
#pragma unroll
        for (int q = 0; q < 2; ++q) {
            int e = lb * 512 + q * 256 + tid;
            unsigned int hv = f2bf(h0all[((e >> 3) & 31) * HID + (e >> 8) * 8 + (e & 7)]);
            GST_U16_SC(hb0 + e, hv);
        }
    } else if (role == 2) {
#pragma unroll
        for (int T = 0; T < 2; ++T) {
            csh[T * 256 + tid] = c0all[32768 + b * HID + j0 + T * 8 + jj];
#pragma unroll
            for (int g = 0; g < 4; ++g)
                bb[T][g] = bih1[g * HID + j0 + T * 8 + jj] + bhh1[g * HID + j0 + T * 8 + jj];
        }
#pragma unroll
        for (int q = 0; q < 2; ++q) {
            int e = lb * 512 + q * 256 + tid;
            unsigned int hv = f2bf(h0all[32768 + ((e >> 3) & 31) * HID + (e >> 8) * 8 + (e & 7)]);
            GST_U16_SC(hb1 + 32768 + e, hv);
        }
    }

    WAIT_VM0();
    __syncthreads();
    if (tid == 0)
        __hip_atomic_store(&flags[bid * 32], 1, __ATOMIC_RELAXED, __HIP_MEMORY_SCOPE_AGENT);

    for (int p = 0; p <= 65; ++p) {
        {
            int g1, t1, g2, t2;
            if (role == 0)      { g1 = 0;   t1 = p + 1; g2 = 64;  t2 = p - 1; }
            else if (role == 1) { g1 = 0;   t1 = p + 1; g2 = 128; t2 = p - 1; }
            else                { g1 = 64;  t1 = p + 1; g2 = 128; t2 = p + 1; }
            if (tid < 64)        poll_group(flags, g1, t1);
            else if (tid < 128)  poll_group(flags, g2, t2);
            __syncthreads();
        }
        const bool active = (role == 0) ? (p <= 63)
                          : (role == 1) ? (p >= 1 && p <= 64)
                                        : (p >= 2);
        if (active) {
            const int t = p - role;
            float pv[2][4];
            if (role == 2) {
                const float* pb = part + (size_t)((p - 2) & 3) * 131072 + lb * 2048 + tid;
#pragma unroll
                for (int T = 0; T < 2; ++T)
#pragma unroll
                    for (int g = 0; g < 4; ++g)
                        GLD_F32_SC(pv[T][g], pb + (T * 4 + g) * 256);
            }
            const unsigned short* hsrc = (role == 2)
                ? hb1 + ((p + 1) & 1) * 32768
                : hb0 + (p & 3) * 32768;
            const unsigned short* hr = hsrc + (size_t)w * 8192 + lane * 8;
            us8 aF[16];
#pragma unroll
            for (int f = 0; f < 16; ++f)
                GLD_US8_SC(aF[f], hr + f * 512);
            WAIT_VM0();
            __builtin_amdgcn_sched_barrier(0);

            f32x16 acc0 = {}, acc1 = {};
#pragma unroll
            for (int f = 0; f < 16; ++f)
                acc0 = __builtin_amdgcn_mfma_f32_32x32x16_bf16(
                    __builtin_bit_cast(bf16x8, aF[f]),
                    __builtin_bit_cast(bf16x8, WB[((0 * 4 + w) * 16 + f) * 64 + lane]),
                    acc0, 0, 0, 0);
#pragma unroll
            for (int f = 0; f < 16; ++f)
                acc1 = __builtin_amdgcn_mfma_f32_32x32x16_bf16(
                    __builtin_bit_cast(bf16x8, aF[f]),
                    __builtin_bit_cast(bf16x8, WB[((1 * 4 + w) * 16 + f) * 64 + lane]),
                    acc1, 0, 0, 0);

#pragma unroll
            for (int T = 0; T < 2; ++T) {
                if (T == 1) __syncthreads();
#pragma unroll
                for (int r = 0; r < 16; ++r) {
                    int m = (r & 3) + 8 * (r >> 2) + 4 * kh;
                    red2[m * 132 + w * 32 + n] = (T == 0) ? acc0[r] : acc1[r];
                }
                __syncthreads();
                float s0, s1, s2, s3;
                {
                    const float* rr = &red2[b * 132 + jj];
                    s0 = rr[0]  + rr[32]  + rr[64]  + rr[96];
                    s1 = rr[8]  + rr[40]  + rr[72]  + rr[104];
                    s2 = rr[16] + rr[48]  + rr[80]  + rr[112];
                    s3 = rr[24] + rr[56]  + rr[88]  + rr[120];
                }
                const int col = j0 + T * 8 + jj;
                const int he  = (lb * 2 + T) * 256 + tid;
                if (role == 1) {
                    float* pdst = part + (size_t)((p - 1) & 3) * 131072 + lb * 2048 + tid;
                    GST_U32_SC(pdst + (T * 4 + 0) * 256, s0);
                    GST_U32_SC(pdst + (T * 4 + 1) * 256, s1);
                    GST_U32_SC(pdst + (T * 4 + 2) * 256, s2);
                    GST_U32_SC(pdst + (T * 4 + 3) * 256, s3);
                } else {
                    if (role == 0) { s0 += gp[T][0]; s1 += gp[T][1]; s2 += gp[T][2]; s3 += gp[T][3]; }
                    else { s0 += pv[T][0] + bb[T][0]; s1 += pv[T][1] + bb[T][1];
                           s2 += pv[T][2] + bb[T][2]; s3 += pv[T][3] + bb[T][3]; }
                    float ig = 1.f / (1.f + expf(-s0));
                    float fg = 1.f / (1.f + expf(-s1));
                    float gg = tanhf(s2);
                    float og = 1.f / (1.f + expf(-s3));
                    float cv = fg * csh[T * 256 + tid] + ig * gg;
                    csh[T * 256 + tid] = cv;
                    float h = og * tanhf(cv);
                    unsigned int hv = f2bf(h);
                    if (role == 0) {
                        GST_U16_SC(hb0 + ((p + 1) & 3) * 32768 + he, hv);
                        if (t == T_STEPS - 1) { hn[b * HID + col] = h; cn[b * HID + col] = cv; }
                    } else {
                        __builtin_nontemporal_store(h, &y1o[(size_t)t * 32768 + b * HID + col]);
                        fin_bf[(size_t)(t * BATCH + b) * 2048 + 1024 + col] = f2bf(h);
                        if (t == T_STEPS - 1) {
                            hn[32768 + b * HID + col] = h;
                            cn[32768 + b * HID + col] = cv;
                        } else {
                            GST_U16_SC(hb1 + (p & 1) * 32768 + he, hv);
                        }
                    }
                }
            }
        }
        if (p < 65) {
            WAIT_VM0();
            __syncthreads();
            if (tid == 0)
                __hip_atomic_store(&flags[bid * 32], p + 2,
                                   __ATOMIC_RELAXED, __HIP_MEMORY_SCOPE_AGENT);
            if (role == 0 && p + 1 <= 63) {
                const float* gsrc = gpre0 + (size_t)((p + 1) * BATCH + b) * 4096 + j0 + jj;
#pragma unroll
                for (int T = 0; T < 2; ++T)
#pragma unroll
                    for (int g = 0; g < 4; ++g)
                        gp[T][g] = gsrc[g * HID + T * 8];
            }
        }
    }
}

// ---------------------------------------------------------------------------
// Fused attention v4 (verified round 14).
// ---------------------------------------------------------------------------
__global__ __launch_bounds__(256) void attn_fused4(
    const float* __restrict__ y1, const float* __restrict__ enc,
    const float* __restrict__ hidden1, const float* __restrict__ aw2,
    const float* __restrict__ ab2, const int* __restrict__ lengths,
    float* __restrict__ ctx, unsigned short* __restrict__ fin_bf)
{
    __shared__ __align__(16) float yl[4][1024];
    __shared__ float sv[4][104];
    __shared__ float av[4][104];
    __shared__ float p4[4];
    __shared__ int   win4[4];
    __shared__ int   winls;
    const int blk  = blockIdx.x;
    const int b    = blk >> 4;
    const int t0   = (blk & 15) * 4;
    const int tid  = threadIdx.x;
    const int wv   = tid >> 6;
    const int lane = tid & 63;
    const int len  = lengths[b];

    for (int i = tid; i < 4096; i += 256) {
        int r = i >> 10, h = i & 1023;
        yl[r][h] = y1[(size_t)((t0 + r) * BATCH + b) * HID + h];
    }

    {
        int row = (t0 + wv) * BATCH + b;
        float s = 0.f;
        for (int i = lane; i < 512; i += 64) s += hidden1[(size_t)row * 512 + i] * aw2[i];
        for (int off = 32; off > 0; off >>= 1) s += __shfl_down(s, off);
        if (lane == 0) {
            float sig = 1.f / (1.f + expf(-(s + ab2[0])));
            float lf = (float)len;
            p4[wv] = (float)WSZ_ + lf * sig;
            win4[wv] = (int)rintf(lf * sig);
        }
        if (wv == 0) {
            int rowl = (T_STEPS - 1) * BATCH + b;
            float s2 = 0.f;
            for (int i = lane; i < 512; i += 64) s2 += hidden1[(size_t)rowl * 512 + i] * aw2[i];
            for (int off = 32; off > 0; off >>= 1) s2 += __shfl_down(s2, off);
            if (lane == 0) {
                float sig = 1.f / (1.f + expf(-(s2 + ab2[0])));
                winls = (int)rintf((float)len * sig);
            }
        }
    }
    __syncthreads();
    const int wl = winls;

    if (tid < WLEN_) {
        const float4* s4p = reinterpret_cast<const float4*>(
            enc + ((size_t)(wl + tid) * BATCH + b) * HID);
        const float4* y0 = reinterpret_cast<const float4*>(yl[0]);
        const float4* y1p = reinterpret_cast<const float4*>(yl[1]);
        const float4* y2 = reinterpret_cast<const float4*>(yl[2]);
        const float4* y3 = reinterpret_cast<const float4*>(yl[3]);
        float a0 = 0.f, a1 = 0.f, a2 = 0.f, a3 = 0.f;
        for (int q = 0; q < 256; ++q) {
            float4 a = s4p[q];
            float4 v0 = y0[q];  a0 += a.x * v0.x + a.y * v0.y + a.z * v0.z + a.w * v0.w;
            float4 v1 = y1p[q]; a1 += a.x * v1.x + a.y * v1.y + a.z * v1.z + a.w * v1.w;
            float4 v2 = y2[q];  a2 += a.x * v2.x + a.y * v2.y + a.z * v2.z + a.w * v2.w;
            float4 v3 = y3[q];  a3 += a.x * v3.x + a.y * v3.y + a.z * v3.z + a.w * v3.w;
        }
        float accs[4] = {a0, a1, a2, a3};
#pragma unroll
        for (int r = 0; r < 4; ++r) {
            bool lo = tid < (WSZ_ - win4[r]);
            bool hi = tid >= (len + WSZ_ - win4[r]);
            sv[r][tid] = (lo || hi) ? 1e-14f : accs[r];
        }
    }
    __syncthreads();

    if (tid < WLEN_) {
#pragma unroll
        for (int r = 0; r < 4; ++r) {
            float mx = -1e30f;
            for (int w = 0; w < WLEN_; ++w) mx = fmaxf(mx, sv[r][w]);
            float sum = 0.f;
            for (int w = 0; w < WLEN_; ++w) sum += expf(sv[r][w] - mx);
            float e = expf(sv[r][tid] - mx) / sum;
            float d = (float)(win4[r] + tid) - p4[r];
            av[r][tid] = e * expf(-(d * d) / 1250.f);
        }
    }
    __syncthreads();

    {
        const int h0 = tid * 4;
        float ac[4][4] = {};
        for (int w = 0; w < WLEN_; ++w) {
            float4 s = *reinterpret_cast<const float4*>(
                enc + ((size_t)(wl + w) * BATCH + b) * HID + h0);
#pragma unroll
            for (int r = 0; r < 4; ++r) {
                float a = av[r][w];
                ac[r][0] += a * s.x; ac[r][1] += a * s.y;
                ac[r][2] += a * s.z; ac[r][3] += a * s.w;
            }
        }
#pragma unroll
        for (int r = 0; r < 4; ++r) {
            size_t row = (size_t)(t0 + r) * BATCH + b;
#pragma unroll
            for (int j = 0; j < 4; ++j) {
                ctx[row * HID + h0 + j] = ac[r][j];
                fin_bf[row * 2048 + h0 + j] = f2bf(ac[r][j]);
            }
        }
    }
}

// ---------------------------------------------------------------------------
__global__ void cvt_bf16_kernel(const float* __restrict__ src,
                                unsigned short* __restrict__ dst, int n8)
{
    for (int i = blockIdx.x * blockDim.x + threadIdx.x; i < n8;
         i += gridDim.x * blockDim.x) {
        float4 v0 = *reinterpret_cast<const float4*>(src + (size_t)i * 8);
        float4 v1 = *reinterpret_cast<const float4*>(src + (size_t)i * 8 + 4);
        us8 c = {f2bf(v0.x), f2bf(v0.y), f2bf(v0.z), f2bf(v0.w),
                 f2bf(v1.x), f2bf(v1.y), f2bf(v1.z), f2bf(v1.w)};
        *reinterpret_cast<us8*>(dst + (size_t)i * 8) = c;
    }
}

// ---------------------------------------------------------------------------
extern "C" void kernel_launch(void* const* d_in, const int* in_sizes, int n_in,
                              void* d_out, int out_size, void* d_ws, size_t ws_size,
                              hipStream_t stream)
{
    const float* enc   = (const float*)d_in[0];
    const float* ctxin = (const float*)d_in[1];
    const float* h0    = (const float*)d_in[2];
    const float* c0    = (const float*)d_in[3];
    const float* emb   = (const float*)d_in[4];
    const float* aw1   = (const float*)d_in[5];
    const float* ab1   = (const float*)d_in[6];
    const float* aw2   = (const float*)d_in[7];
    const float* ab2   = (const float*)d_in[8];
    const float* Wih0  = (const float*)d_in[9];
    const float* Whh0  = (const float*)d_in[10];
    const float* bih0  = (const float*)d_in[11];
    const float* bhh0  = (const float*)d_in[12];
    const float* Wih1  = (const float*)d_in[13];
    const float* Whh1  = (const float*)d_in[14];
    const float* bih1  = (const float*)d_in[15];
    const float* bhh1  = (const float*)d_in[16];
    const float* fc1w  = (const float*)d_in[17];
    const float* fc1b  = (const float*)d_in[18];
    const float* fc2w  = (const float*)d_in[19];
    const float* fc2b  = (const float*)d_in[20];
    const int*   tw    = (const int*)d_in[21];
    const int*   lens  = (const int*)d_in[22];

    float* ws = (float*)d_ws;
    float*          buf_gates = ws;                                   // gpre0
    unsigned short* x_bf      = (unsigned short*)(ws + 8388608);
    float*          buf_part  = ws + 8388608;                         // alias (4 slots)
    unsigned short* Wih0_bf   = (unsigned short*)(ws + 10485760);
    float*          buf_y1    = ws + 16384000;
    unsigned short* buf_hbf   = (unsigned short*)(ws + 18481152);
    int*            buf_flags = (int*)(ws + 18579456);
    float*          buf_hidden1 = ws + 18587904;
    unsigned short* fin_bf    = (unsigned short*)(ws + 22917376);
    unsigned short* fc1w_bf   = (unsigned short*)(ws + 25014528);
    unsigned short* fc1out_bf = (unsigned short*)(ws + 26063104);

    const size_t fold_end_bytes = (size_t)(27111680 + 8192000) * 4;
    const int cvtfc2 = (ws_size >= fold_end_bytes) ? 1 : 0;
    unsigned short* fc2w_bf = cvtfc2 ? (unsigned short*)(ws + 27111680)
                                     : (unsigned short*)ws;   // post-LSTM alias

    float* out   = (float*)d_out;
    float* out_hn  = out + Y_SZ;
    float* out_cn  = out + Y_SZ + HN_SZ;
    float* out_ctx = out + CTX_OFF;

    // 0. fused prep (now includes fc2w convert when workspace allows)
    prep_kernel<<<7585, 256, 0, stream>>>(Wih0, Wih0_bf, fc1w, fc1w_bf,
                                          emb, ctxin, tw, x_bf,
                                          fc2w, fc2w_bf, cvtfc2, buf_flags);

    // 1. gates0_pre = x @ Wih0^T + bih0 + bhh0
    gemm_lds_bt<<<512, 256, 0, stream>>>(
        x_bf, Wih0_bf, bih0, bhh0, buf_gates, nullptr, 2048, 4096, 2048, 0, 0);

    // 2. Both LSTM layers (foldcvt removed — uniform phase work)
    lstm_fused3<<<3 * LBLK, 256, 0, stream>>>(
        buf_gates, Whh0, Wih1, Whh1, bih1, bhh1, h0, c0,
        buf_y1, fin_bf, out_hn, out_cn, buf_hbf, buf_part, buf_flags);

    // 3. fc2 weight convert fallback (only if workspace was too small)
    if (!cvtfc2)
        cvt_bf16_kernel<<<2048, 256, 0, stream>>>(fc2w, fc2w_bf, VOCAB * HID / 8);

    // 4. Attention: hidden1 (fp32 exact) then fused p/win+QK+softmax+PV
    gemm_bt<<<dim3(512 / 64, 2048 / 128), 256, 0, stream>>>(
        buf_y1, aw1, ab1, nullptr, buf_hidden1, 2048, 512, 1024, 2 /*tanh*/);
    attn_fused4<<<512, 256, 0, stream>>>(buf_y1, enc, buf_hidden1, aw2, ab2, lens,
                                         out_ctx, fin_bf);

    // 5. fc1 = relu([ctx, y1] @ fc1_w^T + fc1_b) -> bf16
    gemm_lds_bt<<<128, 256, 0, stream>>>(
        fin_bf, fc1w_bf, fc1b, nullptr, nullptr, fc1out_bf, 2048, 1024, 2048, 1, 0);

    // 6. fc2 -> fp32 d_out (nontemporal)
    gemm_lds_bt<<<4000, 256, 0, stream>>>(
        fc1out_bf, fc2w_bf, fc2b, nullptr, out, nullptr, 2048, VOCAB, 1024, 0, 1);
}

// Round 16
// 931.430 us; speedup vs baseline: 1.0310x; 1.0310x over previous
//
#include <hip/hip_runtime.h>
#include <hip/hip_bf16.h>

// Problem constants
#define T_STEPS 64
#define BATCH   32
#define HID     1024
#define VOCAB   32000
#define WLEN_   101
#define WSZ_    50
#define SENC    229
#define LBLK    64      // blocks per LSTM role; grid = 3*LBLK + 64 cvt = 256

static const size_t Y_SZ   = (size_t)T_STEPS * BATCH * VOCAB;   // 65,536,000
static const size_t HN_SZ  = (size_t)2 * BATCH * HID;           // 65,536
static const size_t CTX_OFF = Y_SZ + 2 * HN_SZ;                 // y + h_n + c_n

typedef __attribute__((ext_vector_type(8)))  unsigned short us8;
typedef __attribute__((ext_vector_type(8)))  __bf16 bf16x8;
typedef __attribute__((ext_vector_type(4)))  float f32x4;
typedef __attribute__((ext_vector_type(16))) float f32x16;

static __device__ inline unsigned short f2bf(float x) {
    __hip_bfloat16 b = __float2bfloat16(x);
    return __builtin_bit_cast(unsigned short, b);
}

// Coherence-point (LLC) accesses for the LSTM cross-block exchange.
#define GLD_US8_SC(dst, ptr) \
    asm volatile("global_load_dwordx4 %0, %1, off sc0 sc1" : "=v"(dst) : "v"(ptr) : "memory")
#define GLD_F32_SC(dst, ptr) \
    asm volatile("global_load_dword %0, %1, off sc0 sc1" : "=v"(dst) : "v"(ptr) : "memory")
#define GST_U16_SC(ptr, val) \
    asm volatile("global_store_short %0, %1, off sc0 sc1" :: "v"(ptr), "v"(val) : "memory")
#define GST_U32_SC(ptr, val) \
    asm volatile("global_store_dword %0, %1, off sc0 sc1" :: "v"(ptr), "v"(val) : "memory")
#define WAIT_VM0() asm volatile("s_waitcnt vmcnt(0)" ::: "memory")

// ---------------------------------------------------------------------------
// fp32 GEMM (attn-proj path only — keeps window indices exact)
// ---------------------------------------------------------------------------
__global__ __launch_bounds__(256) void gemm_bt(
    const float* __restrict__ A, const float* __restrict__ W,
    const float* __restrict__ b1, const float* __restrict__ b2,
    float* __restrict__ out, int M, int N, int K, int act)
{
    __shared__ __align__(16) float As[16 * 132];
    __shared__ __align__(16) float Ws[16 * 68];
    const int tid  = threadIdx.x;
    const int col0 = blockIdx.x * 64;
    const int row0 = blockIdx.y * 128;
    const int ty   = tid >> 4;
    const int tx   = tid & 15;

    float acc[8][4];
#pragma unroll
    for (int i = 0; i < 8; ++i)
#pragma unroll
        for (int j = 0; j < 4; ++j) acc[i][j] = 0.f;

    for (int k0 = 0; k0 < K; k0 += 16) {
#pragma unroll
        for (int li = 0; li < 2; ++li) {
            int f  = tid + li * 256;
            int r  = f >> 2;
            int kq = (f & 3) << 2;
            float4 v = *reinterpret_cast<const float4*>(A + (size_t)(row0 + r) * K + k0 + kq);
            As[(kq + 0) * 132 + r] = v.x;
            As[(kq + 1) * 132 + r] = v.y;
            As[(kq + 2) * 132 + r] = v.z;
            As[(kq + 3) * 132 + r] = v.w;
        }
        {
            int n  = tid >> 2;
            int kq = (tid & 3) << 2;
            float4 v = *reinterpret_cast<const float4*>(W + (size_t)(col0 + n) * K + k0 + kq);
            Ws[(kq + 0) * 68 + n] = v.x;
            Ws[(kq + 1) * 68 + n] = v.y;
            Ws[(kq + 2) * 68 + n] = v.z;
            Ws[(kq + 3) * 68 + n] = v.w;
        }
        __syncthreads();
#pragma unroll
        for (int k = 0; k < 16; ++k) {
            const float4 a0 = *reinterpret_cast<const float4*>(&As[k * 132 + ty * 8]);
            const float4 a1 = *reinterpret_cast<const float4*>(&As[k * 132 + ty * 8 + 4]);
            const float4 b0 = *reinterpret_cast<const float4*>(&Ws[k * 68 + tx * 4]);
            float av[8] = {a0.x, a0.y, a0.z, a0.w, a1.x, a1.y, a1.z, a1.w};
            float bv[4] = {b0.x, b0.y, b0.z, b0.w};
#pragma unroll
            for (int i = 0; i < 8; ++i)
#pragma unroll
                for (int j = 0; j < 4; ++j) acc[i][j] = fmaf(av[i], bv[j], acc[i][j]);
        }
        __syncthreads();
    }

#pragma unroll
    for (int j = 0; j < 4; ++j) {
        int n = col0 + tx * 4 + j;
        float bias = 0.f;
        if (b1) bias += b1[n];
        if (b2) bias += b2[n];
#pragma unroll
        for (int i = 0; i < 8; ++i) {
            float v = acc[i][j] + bias;
            if (act == 1) v = fmaxf(v, 0.f);
            else if (act == 2) v = tanhf(v);
            out[(size_t)(row0 + ty * 8 + i) * N + n] = v;
        }
    }
}

// ---------------------------------------------------------------------------
// bf16 MFMA GEMM, m97-style (verified rounds 8-15). ntout: stream fp32 out.
// ---------------------------------------------------------------------------
__global__ __launch_bounds__(256) void gemm_lds_bt(
    const unsigned short* __restrict__ A, const unsigned short* __restrict__ W,
    const float* __restrict__ b1, const float* __restrict__ b2,
    float* __restrict__ out, unsigned short* __restrict__ out_bf,
    int M, int N, int K, int relu, int ntout)
{
    __shared__ __align__(16) unsigned short As[8192];
    __shared__ __align__(16) unsigned short Ws[8192];
    const int tid  = threadIdx.x;
    const int lane = tid & 63;
    const int wave = tid >> 6;

    const int nwg = gridDim.x;
    const int bid = blockIdx.x;
    const int q = nwg >> 3, r8 = nwg & 7;
    const int xcd = bid & 7, sidx = bid >> 3;
    const int wgid = (xcd < r8 ? xcd * (q + 1) : r8 * (q + 1) + (xcd - r8) * q) + sidx;
    const int mt = M >> 7;
    const int row0 = (wgid % mt) << 7;
    const int col0 = (wgid / mt) << 7;

    const int m0   = (wave >> 1) * 64;
    const int n0   = (wave & 1) * 64;
    const int lrow = lane & 15;
    const int kc   = lane >> 4;

    f32x4 acc[4][4];
#pragma unroll
    for (int i = 0; i < 4; ++i)
#pragma unroll
        for (int j = 0; j < 4; ++j) acc[i][j] = (f32x4){0.f, 0.f, 0.f, 0.f};

    const bool isA = (wave < 2);
    const int  lw  = wave & 1;
    const unsigned short* gbase = isA ? (A + (size_t)row0 * K) : (W + (size_t)col0 * K);
    unsigned short* lbase = isA ? As : Ws;

    for (int k0 = 0; k0 < K; k0 += 64) {
#pragma unroll
        for (int i = 0; i < 8; ++i) {
            const int c    = lw * 512 + i * 64 + lane;
            const int row  = c >> 3;
            const int slot = c & 7;
            const unsigned short* src =
                gbase + (size_t)row * K + k0 + ((slot ^ (row & 7)) << 3);
            __builtin_amdgcn_global_load_lds(
                (const __attribute__((address_space(1))) void*)src,
                (__attribute__((address_space(3))) void*)(lbase + (size_t)(lw * 512 + i * 64) * 8),
                16, 0, 0);
        }
        __syncthreads();
#pragma unroll
        for (int ss = 0; ss < 2; ++ss) {
            us8 a[4], b[4];
#pragma unroll
            for (int f = 0; f < 4; ++f) {
                const int ar = m0 + f * 16 + lrow;
                const int as = (ss * 4 + kc) ^ (ar & 7);
                a[f] = *reinterpret_cast<const us8*>(&As[(ar * 8 + as) * 8]);
                const int br = n0 + f * 16 + lrow;
                const int bs = (ss * 4 + kc) ^ (br & 7);
                b[f] = *reinterpret_cast<const us8*>(&Ws[(br * 8 + bs) * 8]);
            }
#pragma unroll
            for (int fi = 0; fi < 4; ++fi)
#pragma unroll
                for (int fj = 0; fj < 4; ++fj)
                    acc[fi][fj] = __builtin_amdgcn_mfma_f32_16x16x32_bf16(
                        __builtin_bit_cast(bf16x8, a[fi]),
                        __builtin_bit_cast(bf16x8, b[fj]),
                        acc[fi][fj], 0, 0, 0);
        }
        __syncthreads();
    }

#pragma unroll
    for (int fi = 0; fi < 4; ++fi)
#pragma unroll
        for (int fj = 0; fj < 4; ++fj) {
            const int cN = col0 + n0 + fj * 16 + lrow;
            float bv = 0.f;
            if (b1) bv += b1[cN];
            if (b2) bv += b2[cN];
#pragma unroll
            for (int j = 0; j < 4; ++j) {
                const int r = row0 + m0 + fi * 16 + (lane >> 4) * 4 + j;
                float v = acc[fi][fj][j] + bv;
                if (relu) v = fmaxf(v, 0.f);
                if (out) {
                    if (ntout) __builtin_nontemporal_store(v, &out[(size_t)r * N + cN]);
                    else       out[(size_t)r * N + cN] = v;
                }
                if (out_bf) out_bf[(size_t)r * N + cN] = f2bf(v);
            }
        }
}

// ---------------------------------------------------------------------------
// Fused prep: Wih0->bf16, fc1w->bf16, embed+concat->bf16, zero flags.
// (fc2w convert moved to the LSTM's idle-CU D-group.)
// ---------------------------------------------------------------------------
__global__ void prep_kernel(const float* __restrict__ Wih0, unsigned short* __restrict__ Wih0_bf,
                            const float* __restrict__ fc1w, unsigned short* __restrict__ fc1w_bf,
                            const float* __restrict__ emb, const float* __restrict__ ctxin,
                            const int* __restrict__ tw, unsigned short* __restrict__ x_bf,
                            int* __restrict__ flags)
{
    const int bid = blockIdx.x, tid = threadIdx.x;
    if (bid < 2048) {
#pragma unroll
        for (int k = 0; k < 2; ++k) {
            int i = bid * 256 + tid + k * 524288;
            float4 v0 = *reinterpret_cast<const float4*>(Wih0 + (size_t)i * 8);
            float4 v1 = *reinterpret_cast<const float4*>(Wih0 + (size_t)i * 8 + 4);
            us8 c = {f2bf(v0.x), f2bf(v0.y), f2bf(v0.z), f2bf(v0.w),
                     f2bf(v1.x), f2bf(v1.y), f2bf(v1.z), f2bf(v1.w)};
            *reinterpret_cast<us8*>(Wih0_bf + (size_t)i * 8) = c;
        }
    } else if (bid < 3072) {
        int i = (bid - 2048) * 256 + tid;
        float4 v0 = *reinterpret_cast<const float4*>(fc1w + (size_t)i * 8);
        float4 v1 = *reinterpret_cast<const float4*>(fc1w + (size_t)i * 8 + 4);
        us8 c = {f2bf(v0.x), f2bf(v0.y), f2bf(v0.z), f2bf(v0.w),
                 f2bf(v1.x), f2bf(v1.y), f2bf(v1.z), f2bf(v1.w)};
        *reinterpret_cast<us8*>(fc1w_bf + (size_t)i * 8) = c;
    } else if (bid < 3584) {
#pragma unroll
        for (int k = 0; k < 4; ++k) {
            int idx = (bid - 3072) * 256 + tid + k * 131072;
            int row = idx >> 8;
            int c8  = idx & 255;
            const float* src = (c8 < 128)
                ? emb + (size_t)tw[row] * HID + c8 * 8
                : ctxin + (size_t)row * HID + (c8 - 128) * 8;
            float4 v0 = *reinterpret_cast<const float4*>(src);
            float4 v1 = *reinterpret_cast<const float4*>(src + 4);
            us8 c = {f2bf(v0.x), f2bf(v0.y), f2bf(v0.z), f2bf(v0.w),
                     f2bf(v1.x), f2bf(v1.y), f2bf(v1.z), f2bf(v1.w)};
            *reinterpret_cast<us8*>(x_bf + (size_t)idx * 8) = c;
        }
    } else {
        for (int i = tid; i < 6400; i += 256) flags[i] = 0;
    }
}

// ---------------------------------------------------------------------------
// 1-hop scoped barrier: block polls exactly the 64 flags it depends on.
// flags[bid*32] = (last finished phase)+2; init 1 (posted after state init).
// target==1 is the INIT barrier and MUST be polled (round-12 lesson).
// ---------------------------------------------------------------------------
static __device__ inline void poll_group(int* __restrict__ flags, int gbase, int target)
{
    if (target <= 0) return;
    const int lane = threadIdx.x & 63;
    int* fp = &flags[(gbase + lane) * 32];
    for (;;) {
        int f = __hip_atomic_load(fp, __ATOMIC_RELAXED, __HIP_MEMORY_SCOPE_AGENT);
        if (__all(f >= target)) break;
        __builtin_amdgcn_s_sleep(1);
    }
}

// ---------------------------------------------------------------------------
// 3-role fused persistent LSTM + idle-CU D-group (blocks 192..255) that
// streams the fc2w fp32->bf16 convert concurrently (no flags, no barriers;
// hidden under the LSTM's 66 phases; visible to fc2 via kernel boundary).
// ---------------------------------------------------------------------------
__global__ __launch_bounds__(256) void lstm_fused3(
    const float* __restrict__ gpre0,
    const float* __restrict__ Whh0, const float* __restrict__ Wih1,
    const float* __restrict__ Whh1,
    const float* __restrict__ bih1, const float* __restrict__ bhh1,
    const float* __restrict__ h0all, const float* __restrict__ c0all,
    float* __restrict__ y1o,
    unsigned short* __restrict__ fin_bf,
    float* __restrict__ hn, float* __restrict__ cn,
    unsigned short* __restrict__ hbf,
    float* __restrict__ part,
    int* __restrict__ flags,
    const float* __restrict__ fc2w, unsigned short* __restrict__ fc2w_bf,
    int cvtfc2)
{
    const int bid = blockIdx.x;
    const int tid = threadIdx.x;

    // ---- D-group: fc2w convert on the 64 idle CUs ----
    if (bid >= 3 * LBLK) {
        if (cvtfc2) {
            const int cidx = bid - 3 * LBLK;             // 0..63
            const int base = cidx * 64000;               // 4,096,000 chunks / 64
            for (int j = tid; j < 64000; j += 256) {
                int i = base + j;
                float4 v0 = *reinterpret_cast<const float4*>(fc2w + (size_t)i * 8);
                float4 v1 = *reinterpret_cast<const float4*>(fc2w + (size_t)i * 8 + 4);
                us8 c = {f2bf(v0.x), f2bf(v0.y), f2bf(v0.z), f2bf(v0.w),
                         f2bf(v1.x), f2bf(v1.y), f2bf(v1.z), f2bf(v1.w)};
                *reinterpret_cast<us8*>(fc2w_bf + (size_t)i * 8) = c;
            }
        }
        return;
    }

    __shared__ __align__(16) us8 WB[8192];   // 128 KB
    __shared__ float red2[32 * 132];
    __shared__ float csh[512];

    const int lane = tid & 63;
    const int w    = tid >> 6;
    const int n    = lane & 31;
    const int kh   = lane >> 5;
    const int role = bid >> 6;        // 0=A, 1=C, 2=B
    const int lb   = bid & 63;
    const int j0   = lb * 16;
    const int b    = tid >> 3;
    const int jj   = tid & 7;

    unsigned short* hb0 = hbf;            // 4 x 32768
    unsigned short* hb1 = hbf + 131072;   // 2 x 32768

    {
        const float* Wsrc = (role == 0) ? Whh0 : (role == 1 ? Wih1 : Whh1);
        const int g = n >> 3, cj = n & 7;
#pragma unroll
        for (int T = 0; T < 2; ++T) {
            const float* wrow = Wsrc + (size_t)(g * HID + j0 + T * 8 + cj) * HID;
#pragma unroll
            for (int f = 0; f < 16; ++f) {
                int k = w * 256 + f * 16 + kh * 8;
                float4 v0 = *reinterpret_cast<const float4*>(wrow + k);
                float4 v1 = *reinterpret_cast<const float4*>(wrow + k + 4);
                WB[((T * 4 + w) * 16 + f) * 64 + lane] =
                    (us8){f2bf(v0.x), f2bf(v0.y), f2bf(v0.z), f2bf(v0.w),
                          f2bf(v1.x), f2bf(v1.y), f2bf(v1.z), f2bf(v1.w)};
            }
        }
    }

    float gp[2][4] = {};
    float bb[2][4] = {};
    if (role == 0) {
#pragma unroll
        for (int T = 0; T < 2; ++T) {
            csh[T * 256 + tid] = c0all[b * HID + j0 + T * 8 + jj];
#pragma unroll
            for (int g = 0; g < 4; ++g)
                gp[T][g] = gpre0[(size_t)b * 4096 + g * HID + j0 + T * 8 + jj];
        }
#pragma unroll
        for (int q = 0; q < 2; ++q) {
            int e = lb * 512 + q * 256 + tid;
            unsigned int hv = f2bf(h0all[((e >> 3) & 31) * HID + (e >> 8) * 8 + (e & 7)]);
            GST_U16_SC(hb0 + e, hv);
        }
    } else if (role == 2) {
#pragma unroll
        for (int T = 0; T < 2; ++T) {
            csh[T * 256 + tid] = c0all[32768 + b * HID + j0 + T * 8 + jj];
#pragma unroll
            for (int g = 0; g < 4; ++g)
                bb[T][g] = bih1[g * HID + j0 + T * 8 + jj] + bhh1[g * HID + j0 + T * 8 + jj];
        }
#pragma unroll
        for (int q = 0; q < 2; ++q) {
            int e = lb * 512 + q * 256 + tid;
            unsigned int hv = f2bf(h0all[32768 + ((e >> 3) & 31) * HID + (e >> 8) * 8 + (e & 7)]);
            GST_U16_SC(hb1 + 32768 + e, hv);
        }
    }

    WAIT_VM0();
    __syncthreads();
    if (tid == 0)
        __hip_atomic_store(&flags[bid * 32], 1, __ATOMIC_RELAXED, __HIP_MEMORY_SCOPE_AGENT);

    for (int p = 0; p <= 65; ++p) {
        {
            int g1, t1, g2, t2;
            if (role == 0)      { g1 = 0;   t1 = p + 1; g2 = 64;  t2 = p - 1; }
            else if (role == 1) { g1 = 0;   t1 = p + 1; g2 = 128; t2 = p - 1; }
            else                { g1 = 64;  t1 = p + 1; g2 = 128; t2 = p + 1; }
            if (tid < 64)        poll_group(flags, g1, t1);
            else if (tid < 128)  poll_group(flags, g2, t2);
            __syncthreads();
        }
        const bool active = (role == 0) ? (p <= 63)
                          : (role == 1) ? (p >= 1 && p <= 64)
                                        : (p >= 2);
        if (active) {
            const int t = p - role;
            float pv[2][4];
            if (role == 2) {
                const float* pb = part + (size_t)((p - 2) & 3) * 131072 + lb * 2048 + tid;
#pragma unroll
                for (int T = 0; T < 2; ++T)
#pragma unroll
                    for (int g = 0; g < 4; ++g)
                        GLD_F32_SC(pv[T][g], pb + (T * 4 + g) * 256);
            }
            const unsigned short* hsrc = (role == 2)
                ? hb1 + ((p + 1) & 1) * 32768
                : hb0 + (p & 3) * 32768;
            const unsigned short* hr = hsrc + (size_t)w * 8192 + lane * 8;
            us8 aF[16];
#pragma unroll
            for (int f = 0; f < 16; ++f)
                GLD_US8_SC(aF[f], hr + f * 512);
            WAIT_VM0();
            __builtin_amdgcn_sched_barrier(0);

            f32x16 acc0 = {}, acc1 = {};
#pragma unroll
            for (int f = 0; f < 16; ++f)
                acc0 = __builtin_amdgcn_mfma_f32_32x32x16_bf16(
                    __builtin_bit_cast(bf16x8, aF[f]),
                    __builtin_bit_cast(bf16x8, WB[((0 * 4 + w) * 16 + f) * 64 + lane]),
                    acc0, 0, 0, 0);
#pragma unroll
            for (int f = 0; f < 16; ++f)
                acc1 = __builtin_amdgcn_mfma_f32_32x32x16_bf16(
                    __builtin_bit_cast(bf16x8, aF[f]),
                    __builtin_bit_cast(bf16x8, WB[((1 * 4 + w) * 16 + f) * 64 + lane]),
                    acc1, 0, 0, 0);

#pragma unroll
            for (int T = 0; T < 2; ++T) {
                if (T == 1) __syncthreads();
#pragma unroll
                for (int r = 0; r < 16; ++r) {
                    int m = (r & 3) + 8 * (r >> 2) + 4 * kh;
                    red2[m * 132 + w * 32 + n] = (T == 0) ? acc0[r] : acc1[r];
                }
                __syncthreads();
                float s0, s1, s2, s3;
                {
                    const float* rr = &red2[b * 132 + jj];
                    s0 = rr[0]  + rr[32]  + rr[64]  + rr[96];
                    s1 = rr[8]  + rr[40]  + rr[72]  + rr[104];
                    s2 = rr[16] + rr[48]  + rr[80]  + rr[112];
                    s3 = rr[24] + rr[56]  + rr[88]  + rr[120];
                }
                const int col = j0 + T * 8 + jj;
                const int he  = (lb * 2 + T) * 256 + tid;
                if (role == 1) {
                    float* pdst = part + (size_t)((p - 1) & 3) * 131072 + lb * 2048 + tid;
                    GST_U32_SC(pdst + (T * 4 + 0) * 256, s0);
                    GST_U32_SC(pdst + (T * 4 + 1) * 256, s1);
                    GST_U32_SC(pdst + (T * 4 + 2) * 256, s2);
                    GST_U32_SC(pdst + (T * 4 + 3) * 256, s3);
                } else {
                    if (role == 0) { s0 += gp[T][0]; s1 += gp[T][1]; s2 += gp[T][2]; s3 += gp[T][3]; }
                    else { s0 += pv[T][0] + bb[T][0]; s1 += pv[T][1] + bb[T][1];
                           s2 += pv[T][2] + bb[T][2]; s3 += pv[T][3] + bb[T][3]; }
                    float ig = 1.f / (1.f + expf(-s0));
                    float fg = 1.f / (1.f + expf(-s1));
                    float gg = tanhf(s2);
                    float og = 1.f / (1.f + expf(-s3));
                    float cv = fg * csh[T * 256 + tid] + ig * gg;
                    csh[T * 256 + tid] = cv;
                    float h = og * tanhf(cv);
                    unsigned int hv = f2bf(h);
                    if (role == 0) {
                        GST_U16_SC(hb0 + ((p + 1) & 3) * 32768 + he, hv);
                        if (t == T_STEPS - 1) { hn[b * HID + col] = h; cn[b * HID + col] = cv; }
                    } else {
                        __builtin_nontemporal_store(h, &y1o[(size_t)t * 32768 + b * HID + col]);
                        fin_bf[(size_t)(t * BATCH + b) * 2048 + 1024 + col] = f2bf(h);
                        if (t == T_STEPS - 1) {
                            hn[32768 + b * HID + col] = h;
                            cn[32768 + b * HID + col] = cv;
                        } else {
                            GST_U16_SC(hb1 + (p & 1) * 32768 + he, hv);
                        }
                    }
                }
            }
        }
        if (p < 65) {
            WAIT_VM0();
            __syncthreads();
            if (tid == 0)
                __hip_atomic_store(&flags[bid * 32], p + 2,
                                   __ATOMIC_RELAXED, __HIP_MEMORY_SCOPE_AGENT);
            if (role == 0 && p + 1 <= 63) {
                const float* gsrc = gpre0 + (size_t)((p + 1) * BATCH + b) * 4096 + j0 + jj;
#pragma unroll
                for (int T = 0; T < 2; ++T)
#pragma unroll
                    for (int g = 0; g < 4; ++g)
                        gp[T][g] = gsrc[g * HID + T * 8];
            }
        }
    }
}

// ---------------------------------------------------------------------------
// Fused attention v4 (verified round 14).
// ---------------------------------------------------------------------------
__global__ __launch_bounds__(256) void attn_fused4(
    const float* __restrict__ y1, const float* __restrict__ enc,
    const float* __restrict__ hidden1, const float* __restrict__ aw2,
    const float* __restrict__ ab2, const int* __restrict__ lengths,
    float* __restrict__ ctx, unsigned short* __restrict__ fin_bf)
{
    __shared__ __align__(16) float yl[4][1024];
    __shared__ float sv[4][104];
    __shared__ float av[4][104];
    __shared__ float p4[4];
    __shared__ int   win4[4];
    __shared__ int   winls;
    const int blk  = blockIdx.x;
    const int b    = blk >> 4;
    const int t0   = (blk & 15) * 4;
    const int tid  = threadIdx.x;
    const int wv   = tid >> 6;
    const int lane = tid & 63;
    const int len  = lengths[b];

    for (int i = tid; i < 4096; i += 256) {
        int r = i >> 10, h = i & 1023;
        yl[r][h] = y1[(size_t)((t0 + r) * BATCH + b) * HID + h];
    }

    {
        int row = (t0 + wv) * BATCH + b;
        float s = 0.f;
        for (int i = lane; i < 512; i += 64) s += hidden1[(size_t)row * 512 + i] * aw2[i];
        for (int off = 32; off > 0; off >>= 1) s += __shfl_down(s, off);
        if (lane == 0) {
            float sig = 1.f / (1.f + expf(-(s + ab2[0])));
            float lf = (float)len;
            p4[wv] = (float)WSZ_ + lf * sig;
            win4[wv] = (int)rintf(lf * sig);
        }
        if (wv == 0) {
            int rowl = (T_STEPS - 1) * BATCH + b;
            float s2 = 0.f;
            for (int i = lane; i < 512; i += 64) s2 += hidden1[(size_t)rowl * 512 + i] * aw2[i];
            for (int off = 32; off > 0; off >>= 1) s2 += __shfl_down(s2, off);
            if (lane == 0) {
                float sig = 1.f / (1.f + expf(-(s2 + ab2[0])));
                winls = (int)rintf((float)len * sig);
            }
        }
    }
    __syncthreads();
    const int wl = winls;

    if (tid < WLEN_) {
        const float4* s4p = reinterpret_cast<const float4*>(
            enc + ((size_t)(wl + tid) * BATCH + b) * HID);
        const float4* y0 = reinterpret_cast<const float4*>(yl[0]);
        const float4* y1p = reinterpret_cast<const float4*>(yl[1]);
        const float4* y2 = reinterpret_cast<const float4*>(yl[2]);
        const float4* y3 = reinterpret_cast<const float4*>(yl[3]);
        float a0 = 0.f, a1 = 0.f, a2 = 0.f, a3 = 0.f;
        for (int q = 0; q < 256; ++q) {
            float4 a = s4p[q];
            float4 v0 = y0[q];  a0 += a.x * v0.x + a.y * v0.y + a.z * v0.z + a.w * v0.w;
            float4 v1 = y1p[q]; a1 += a.x * v1.x + a.y * v1.y + a.z * v1.z + a.w * v1.w;
            float4 v2 = y2[q];  a2 += a.x * v2.x + a.y * v2.y + a.z * v2.z + a.w * v2.w;
            float4 v3 = y3[q];  a3 += a.x * v3.x + a.y * v3.y + a.z * v3.z + a.w * v3.w;
        }
        float accs[4] = {a0, a1, a2, a3};
#pragma unroll
        for (int r = 0; r < 4; ++r) {
            bool lo = tid < (WSZ_ - win4[r]);
            bool hi = tid >= (len + WSZ_ - win4[r]);
            sv[r][tid] = (lo || hi) ? 1e-14f : accs[r];
        }
    }
    __syncthreads();

    if (tid < WLEN_) {
#pragma unroll
        for (int r = 0; r < 4; ++r) {
            float mx = -1e30f;
            for (int w = 0; w < WLEN_; ++w) mx = fmaxf(mx, sv[r][w]);
            float sum = 0.f;
            for (int w = 0; w < WLEN_; ++w) sum += expf(sv[r][w] - mx);
            float e = expf(sv[r][tid] - mx) / sum;
            float d = (float)(win4[r] + tid) - p4[r];
            av[r][tid] = e * expf(-(d * d) / 1250.f);
        }
    }
    __syncthreads();

    {
        const int h0 = tid * 4;
        float ac[4][4] = {};
        for (int w = 0; w < WLEN_; ++w) {
            float4 s = *reinterpret_cast<const float4*>(
                enc + ((size_t)(wl + w) * BATCH + b) * HID + h0);
#pragma unroll
            for (int r = 0; r < 4; ++r) {
                float a = av[r][w];
                ac[r][0] += a * s.x; ac[r][1] += a * s.y;
                ac[r][2] += a * s.z; ac[r][3] += a * s.w;
            }
        }
#pragma unroll
        for (int r = 0; r < 4; ++r) {
            size_t row = (size_t)(t0 + r) * BATCH + b;
#pragma unroll
            for (int j = 0; j < 4; ++j) {
                ctx[row * HID + h0 + j] = ac[r][j];
                fin_bf[row * 2048 + h0 + j] = f2bf(ac[r][j]);
            }
        }
    }
}

// ---------------------------------------------------------------------------
__global__ void cvt_bf16_kernel(const float* __restrict__ src,
                                unsigned short* __restrict__ dst, int n8)
{
    for (int i = blockIdx.x * blockDim.x + threadIdx.x; i < n8;
         i += gridDim.x * blockDim.x) {
        float4 v0 = *reinterpret_cast<const float4*>(src + (size_t)i * 8);
        float4 v1 = *reinterpret_cast<const float4*>(src + (size_t)i * 8 + 4);
        us8 c = {f2bf(v0.x), f2bf(v0.y), f2bf(v0.z), f2bf(v0.w),
                 f2bf(v1.x), f2bf(v1.y), f2bf(v1.z), f2bf(v1.w)};
        *reinterpret_cast<us8*>(dst + (size_t)i * 8) = c;
    }
}

// ---------------------------------------------------------------------------
extern "C" void kernel_launch(void* const* d_in, const int* in_sizes, int n_in,
                              void* d_out, int out_size, void* d_ws, size_t ws_size,
                              hipStream_t stream)
{
    const float* enc   = (const float*)d_in[0];
    const float* ctxin = (const float*)d_in[1];
    const float* h0    = (const float*)d_in[2];
    const float* c0    = (const float*)d_in[3];
    const float* emb   = (const float*)d_in[4];
    const float* aw1   = (const float*)d_in[5];
    const float* ab1   = (const float*)d_in[6];
    const float* aw2   = (const float*)d_in[7];
    const float* ab2   = (const float*)d_in[8];
    const float* Wih0  = (const float*)d_in[9];
    const float* Whh0  = (const float*)d_in[10];
    const float* bih0  = (const float*)d_in[11];
    const float* bhh0  = (const float*)d_in[12];
    const float* Wih1  = (const float*)d_in[13];
    const float* Whh1  = (const float*)d_in[14];
    const float* bih1  = (const float*)d_in[15];
    const float* bhh1  = (const float*)d_in[16];
    const float* fc1w  = (const float*)d_in[17];
    const float* fc1b  = (const float*)d_in[18];
    const float* fc2w  = (const float*)d_in[19];
    const float* fc2b  = (const float*)d_in[20];
    const int*   tw    = (const int*)d_in[21];
    const int*   lens  = (const int*)d_in[22];

    float* ws = (float*)d_ws;
    float*          buf_gates = ws;                                   // gpre0
    unsigned short* x_bf      = (unsigned short*)(ws + 8388608);
    float*          buf_part  = ws + 8388608;                         // alias (4 slots)
    unsigned short* Wih0_bf   = (unsigned short*)(ws + 10485760);
    float*          buf_y1    = ws + 16384000;
    unsigned short* buf_hbf   = (unsigned short*)(ws + 18481152);
    int*            buf_flags = (int*)(ws + 18579456);
    float*          buf_hidden1 = ws + 18587904;
    unsigned short* fin_bf    = (unsigned short*)(ws + 22917376);
    unsigned short* fc1w_bf   = (unsigned short*)(ws + 25014528);
    unsigned short* fc1out_bf = (unsigned short*)(ws + 26063104);

    const size_t fold_end_bytes = (size_t)(27111680 + 8192000) * 4;
    const int cvtfc2 = (ws_size >= fold_end_bytes) ? 1 : 0;
    unsigned short* fc2w_bf = cvtfc2 ? (unsigned short*)(ws + 27111680)
                                     : (unsigned short*)ws;   // post-LSTM alias

    float* out   = (float*)d_out;
    float* out_hn  = out + Y_SZ;
    float* out_cn  = out + Y_SZ + HN_SZ;
    float* out_ctx = out + CTX_OFF;

    // 0. fused prep (fc2w convert removed — it rides the LSTM's idle CUs)
    prep_kernel<<<3585, 256, 0, stream>>>(Wih0, Wih0_bf, fc1w, fc1w_bf,
                                          emb, ctxin, tw, x_bf, buf_flags);

    // 1. gates0_pre = x @ Wih0^T + bih0 + bhh0
    gemm_lds_bt<<<512, 256, 0, stream>>>(
        x_bf, Wih0_bf, bih0, bhh0, buf_gates, nullptr, 2048, 4096, 2048, 0, 0);

    // 2. Both LSTM layers + D-group fc2w convert on idle CUs (grid 256)
    lstm_fused3<<<3 * LBLK + 64, 256, 0, stream>>>(
        buf_gates, Whh0, Wih1, Whh1, bih1, bhh1, h0, c0,
        buf_y1, fin_bf, out_hn, out_cn, buf_hbf, buf_part, buf_flags,
        fc2w, fc2w_bf, cvtfc2);

    // 3. fc2 weight convert fallback (only if workspace was too small)
    if (!cvtfc2)
        cvt_bf16_kernel<<<2048, 256, 0, stream>>>(fc2w, fc2w_bf, VOCAB * HID / 8);

    // 4. Attention: hidden1 (fp32 exact) then fused p/win+QK+softmax+PV
    gemm_bt<<<dim3(512 / 64, 2048 / 128), 256, 0, stream>>>(
        buf_y1, aw1, ab1, nullptr, buf_hidden1, 2048, 512, 1024, 2 /*tanh*/);
    attn_fused4<<<512, 256, 0, stream>>>(buf_y1, enc, buf_hidden1, aw2, ab2, lens,
                                         out_ctx, fin_bf);

    // 5. fc1 = relu([ctx, y1] @ fc1_w^T + fc1_b) -> bf16
    gemm_lds_bt<<<128, 256, 0, stream>>>(
        fin_bf, fc1w_bf, fc1b, nullptr, nullptr, fc1out_bf, 2048, 1024, 2048, 1, 0);

    // 6. fc2 -> fp32 d_out (nontemporal)
    gemm_lds_bt<<<4000, 256, 0, stream>>>(
        fc1out_bf, fc2w_bf, fc2b, nullptr, out, nullptr, 2048, VOCAB, 1024, 0, 1);
}

// Round 18
// 923.641 us; speedup vs baseline: 1.0397x; 1.0084x over previous
//
#include <hip/hip_runtime.h>
#include <hip/hip_bf16.h>

// Problem constants
#define T_STEPS 64
#define BATCH   32
#define HID     1024
#define VOCAB   32000
#define WLEN_   101
#define WSZ_    50
#define SENC    229
#define LBLK    64      // blocks per LSTM role; grid = 3*LBLK + 64 cvt = 256

static const size_t Y_SZ   = (size_t)T_STEPS * BATCH * VOCAB;   // 65,536,000
static const size_t HN_SZ  = (size_t)2 * BATCH * HID;           // 65,536
static const size_t CTX_OFF = Y_SZ + 2 * HN_SZ;                 // y + h_n + c_n

typedef __attribute__((ext_vector_type(8)))  unsigned short us8;
typedef __attribute__((ext_vector_type(8)))  __bf16 bf16x8;
typedef __attribute__((ext_vector_type(4)))  float f32x4;
typedef __attribute__((ext_vector_type(16))) float f32x16;

static __device__ inline unsigned short f2bf(float x) {
    __hip_bfloat16 b = __float2bfloat16(x);
    return __builtin_bit_cast(unsigned short, b);
}

// Coherence-point (LLC) accesses for the LSTM cross-block exchange.
#define GLD_US8_SC(dst, ptr) \
    asm volatile("global_load_dwordx4 %0, %1, off sc0 sc1" : "=v"(dst) : "v"(ptr) : "memory")
#define GLD_F32X4_SC(dst, ptr) \
    asm volatile("global_load_dwordx4 %0, %1, off sc0 sc1" : "=v"(dst) : "v"(ptr) : "memory")
#define GST_U16_SC(ptr, val) \
    asm volatile("global_store_short %0, %1, off sc0 sc1" :: "v"(ptr), "v"(val) : "memory")
#define GST_F32X4_SC(ptr, val) \
    asm volatile("global_store_dwordx4 %0, %1, off sc0 sc1" :: "v"(ptr), "v"(val) : "memory")
#define WAIT_VM0() asm volatile("s_waitcnt vmcnt(0)" ::: "memory")

// ---------------------------------------------------------------------------
// fp32 GEMM (attn-proj path only — keeps window indices exact)
// ---------------------------------------------------------------------------
__global__ __launch_bounds__(256) void gemm_bt(
    const float* __restrict__ A, const float* __restrict__ W,
    const float* __restrict__ b1, const float* __restrict__ b2,
    float* __restrict__ out, int M, int N, int K, int act)
{
    __shared__ __align__(16) float As[16 * 132];
    __shared__ __align__(16) float Ws[16 * 68];
    const int tid  = threadIdx.x;
    const int col0 = blockIdx.x * 64;
    const int row0 = blockIdx.y * 128;
    const int ty   = tid >> 4;
    const int tx   = tid & 15;

    float acc[8][4];
#pragma unroll
    for (int i = 0; i < 8; ++i)
#pragma unroll
        for (int j = 0; j < 4; ++j) acc[i][j] = 0.f;

    for (int k0 = 0; k0 < K; k0 += 16) {
#pragma unroll
        for (int li = 0; li < 2; ++li) {
            int f  = tid + li * 256;
            int r  = f >> 2;
            int kq = (f & 3) << 2;
            float4 v = *reinterpret_cast<const float4*>(A + (size_t)(row0 + r) * K + k0 + kq);
            As[(kq + 0) * 132 + r] = v.x;
            As[(kq + 1) * 132 + r] = v.y;
            As[(kq + 2) * 132 + r] = v.z;
            As[(kq + 3) * 132 + r] = v.w;
        }
        {
            int n  = tid >> 2;
            int kq = (tid & 3) << 2;
            float4 v = *reinterpret_cast<const float4*>(W + (size_t)(col0 + n) * K + k0 + kq);
            Ws[(kq + 0) * 68 + n] = v.x;
            Ws[(kq + 1) * 68 + n] = v.y;
            Ws[(kq + 2) * 68 + n] = v.z;
            Ws[(kq + 3) * 68 + n] = v.w;
        }
        __syncthreads();
#pragma unroll
        for (int k = 0; k < 16; ++k) {
            const float4 a0 = *reinterpret_cast<const float4*>(&As[k * 132 + ty * 8]);
            const float4 a1 = *reinterpret_cast<const float4*>(&As[k * 132 + ty * 8 + 4]);
            const float4 b0 = *reinterpret_cast<const float4*>(&Ws[k * 68 + tx * 4]);
            float av[8] = {a0.x, a0.y, a0.z, a0.w, a1.x, a1.y, a1.z, a1.w};
            float bv[4] = {b0.x, b0.y, b0.z, b0.w};
#pragma unroll
            for (int i = 0; i < 8; ++i)
#pragma unroll
                for (int j = 0; j < 4; ++j) acc[i][j] = fmaf(av[i], bv[j], acc[i][j]);
        }
        __syncthreads();
    }

#pragma unroll
    for (int j = 0; j < 4; ++j) {
        int n = col0 + tx * 4 + j;
        float bias = 0.f;
        if (b1) bias += b1[n];
        if (b2) bias += b2[n];
#pragma unroll
        for (int i = 0; i < 8; ++i) {
            float v = acc[i][j] + bias;
            if (act == 1) v = fmaxf(v, 0.f);
            else if (act == 2) v = tanhf(v);
            out[(size_t)(row0 + ty * 8 + i) * N + n] = v;
        }
    }
}

// ---------------------------------------------------------------------------
// bf16 MFMA GEMM, m97-style (verified rounds 8-16). ntout: stream fp32 out.
// ---------------------------------------------------------------------------
__global__ __launch_bounds__(256) void gemm_lds_bt(
    const unsigned short* __restrict__ A, const unsigned short* __restrict__ W,
    const float* __restrict__ b1, const float* __restrict__ b2,
    float* __restrict__ out, unsigned short* __restrict__ out_bf,
    int M, int N, int K, int relu, int ntout)
{
    __shared__ __align__(16) unsigned short As[8192];
    __shared__ __align__(16) unsigned short Ws[8192];
    const int tid  = threadIdx.x;
    const int lane = tid & 63;
    const int wave = tid >> 6;

    const int nwg = gridDim.x;
    const int bid = blockIdx.x;
    const int q = nwg >> 3, r8 = nwg & 7;
    const int xcd = bid & 7, sidx = bid >> 3;
    const int wgid = (xcd < r8 ? xcd * (q + 1) : r8 * (q + 1) + (xcd - r8) * q) + sidx;
    const int mt = M >> 7;
    const int row0 = (wgid % mt) << 7;
    const int col0 = (wgid / mt) << 7;

    const int m0   = (wave >> 1) * 64;
    const int n0   = (wave & 1) * 64;
    const int lrow = lane & 15;
    const int kc   = lane >> 4;

    f32x4 acc[4][4];
#pragma unroll
    for (int i = 0; i < 4; ++i)
#pragma unroll
        for (int j = 0; j < 4; ++j) acc[i][j] = (f32x4){0.f, 0.f, 0.f, 0.f};

    const bool isA = (wave < 2);
    const int  lw  = wave & 1;
    const unsigned short* gbase = isA ? (A + (size_t)row0 * K) : (W + (size_t)col0 * K);
    unsigned short* lbase = isA ? As : Ws;

    for (int k0 = 0; k0 < K; k0 += 64) {
#pragma unroll
        for (int i = 0; i < 8; ++i) {
            const int c    = lw * 512 + i * 64 + lane;
            const int row  = c >> 3;
            const int slot = c & 7;
            const unsigned short* src =
                gbase + (size_t)row * K + k0 + ((slot ^ (row & 7)) << 3);
            __builtin_amdgcn_global_load_lds(
                (const __attribute__((address_space(1))) void*)src,
                (__attribute__((address_space(3))) void*)(lbase + (size_t)(lw * 512 + i * 64) * 8),
                16, 0, 0);
        }
        __syncthreads();
#pragma unroll
        for (int ss = 0; ss < 2; ++ss) {
            us8 a[4], b[4];
#pragma unroll
            for (int f = 0; f < 4; ++f) {
                const int ar = m0 + f * 16 + lrow;
                const int as = (ss * 4 + kc) ^ (ar & 7);
                a[f] = *reinterpret_cast<const us8*>(&As[(ar * 8 + as) * 8]);
                const int br = n0 + f * 16 + lrow;
                const int bs = (ss * 4 + kc) ^ (br & 7);
                b[f] = *reinterpret_cast<const us8*>(&Ws[(br * 8 + bs) * 8]);
            }
#pragma unroll
            for (int fi = 0; fi < 4; ++fi)
#pragma unroll
                for (int fj = 0; fj < 4; ++fj)
                    acc[fi][fj] = __builtin_amdgcn_mfma_f32_16x16x32_bf16(
                        __builtin_bit_cast(bf16x8, a[fi]),
                        __builtin_bit_cast(bf16x8, b[fj]),
                        acc[fi][fj], 0, 0, 0);
        }
        __syncthreads();
    }

#pragma unroll
    for (int fi = 0; fi < 4; ++fi)
#pragma unroll
        for (int fj = 0; fj < 4; ++fj) {
            const int cN = col0 + n0 + fj * 16 + lrow;
            float bv = 0.f;
            if (b1) bv += b1[cN];
            if (b2) bv += b2[cN];
#pragma unroll
            for (int j = 0; j < 4; ++j) {
                const int r = row0 + m0 + fi * 16 + (lane >> 4) * 4 + j;
                float v = acc[fi][fj][j] + bv;
                if (relu) v = fmaxf(v, 0.f);
                if (out) {
                    if (ntout) __builtin_nontemporal_store(v, &out[(size_t)r * N + cN]);
                    else       out[(size_t)r * N + cN] = v;
                }
                if (out_bf) out_bf[(size_t)r * N + cN] = f2bf(v);
            }
        }
}

// ---------------------------------------------------------------------------
// Fused prep: Wih0->bf16, fc1w->bf16, embed+concat->bf16, zero flags.
// ---------------------------------------------------------------------------
__global__ void prep_kernel(const float* __restrict__ Wih0, unsigned short* __restrict__ Wih0_bf,
                            const float* __restrict__ fc1w, unsigned short* __restrict__ fc1w_bf,
                            const float* __restrict__ emb, const float* __restrict__ ctxin,
                            const int* __restrict__ tw, unsigned short* __restrict__ x_bf,
                            int* __restrict__ flags)
{
    const int bid = blockIdx.x, tid = threadIdx.x;
    if (bid < 2048) {
#pragma unroll
        for (int k = 0; k < 2; ++k) {
            int i = bid * 256 + tid + k * 524288;
            float4 v0 = *reinterpret_cast<const float4*>(Wih0 + (size_t)i * 8);
            float4 v1 = *reinterpret_cast<const float4*>(Wih0 + (size_t)i * 8 + 4);
            us8 c = {f2bf(v0.x), f2bf(v0.y), f2bf(v0.z), f2bf(v0.w),
                     f2bf(v1.x), f2bf(v1.y), f2bf(v1.z), f2bf(v1.w)};
            *reinterpret_cast<us8*>(Wih0_bf + (size_t)i * 8) = c;
        }
    } else if (bid < 3072) {
        int i = (bid - 2048) * 256 + tid;
        float4 v0 = *reinterpret_cast<const float4*>(fc1w + (size_t)i * 8);
        float4 v1 = *reinterpret_cast<const float4*>(fc1w + (size_t)i * 8 + 4);
        us8 c = {f2bf(v0.x), f2bf(v0.y), f2bf(v0.z), f2bf(v0.w),
                 f2bf(v1.x), f2bf(v1.y), f2bf(v1.z), f2bf(v1.w)};
        *reinterpret_cast<us8*>(fc1w_bf + (size_t)i * 8) = c;
    } else if (bid < 3584) {
#pragma unroll
        for (int k = 0; k < 4; ++k) {
            int idx = (bid - 3072) * 256 + tid + k * 131072;
            int row = idx >> 8;
            int c8  = idx & 255;
            const float* src = (c8 < 128)
                ? emb + (size_t)tw[row] * HID + c8 * 8
                : ctxin + (size_t)row * HID + (c8 - 128) * 8;
            float4 v0 = *reinterpret_cast<const float4*>(src);
            float4 v1 = *reinterpret_cast<const float4*>(src + 4);
            us8 c = {f2bf(v0.x), f2bf(v0.y), f2bf(v0.z), f2bf(v0.w),
                     f2bf(v1.x), f2bf(v1.y), f2bf(v1.z), f2bf(v1.w)};
            *reinterpret_cast<us8*>(x_bf + (size_t)idx * 8) = c;
        }
    } else {
        for (int i = tid; i < 6400; i += 256) flags[i] = 0;
    }
}

// ---------------------------------------------------------------------------
// 1-hop scoped barrier: block polls exactly the 64 flags it depends on.
// flags[bid*32] = (last finished phase)+2; init 1 (posted after state init).
// target==1 is the INIT barrier and MUST be polled (round-12 lesson).
// ---------------------------------------------------------------------------
static __device__ inline void poll_group(int* __restrict__ flags, int gbase, int target)
{
    if (target <= 0) return;
    const int lane = threadIdx.x & 63;
    int* fp = &flags[(gbase + lane) * 32];
    for (;;) {
        int f = __hip_atomic_load(fp, __ATOMIC_RELAXED, __HIP_MEMORY_SCOPE_AGENT);
        if (__all(f >= target)) break;
        __builtin_amdgcn_s_sleep(1);
    }
}

// ---------------------------------------------------------------------------
// 3-role fused persistent LSTM + idle-CU D-group (blocks 192..255) that
// streams the fc2w fp32->bf16 convert concurrently (nontemporal — no LLC
// pollution of the sc0sc1 h-exchange). C<->B partial exchange vectorized to
// float4 (layout part[slot][lb][T*1024 + tid*4 + g], coalesced, same order).
// ---------------------------------------------------------------------------
__global__ __launch_bounds__(256) void lstm_fused3(
    const float* __restrict__ gpre0,
    const float* __restrict__ Whh0, const float* __restrict__ Wih1,
    const float* __restrict__ Whh1,
    const float* __restrict__ bih1, const float* __restrict__ bhh1,
    const float* __restrict__ h0all, const float* __restrict__ c0all,
    float* __restrict__ y1o,
    unsigned short* __restrict__ fin_bf,
    float* __restrict__ hn, float* __restrict__ cn,
    unsigned short* __restrict__ hbf,
    float* __restrict__ part,
    int* __restrict__ flags,
    const float* __restrict__ fc2w, unsigned short* __restrict__ fc2w_bf,
    int cvtfc2)
{
    const int bid = blockIdx.x;
    const int tid = threadIdx.x;

    // ---- D-group: fc2w convert on the 64 idle CUs (nontemporal) ----
    if (bid >= 3 * LBLK) {
        if (cvtfc2) {
            const int cidx = bid - 3 * LBLK;             // 0..63
            const int base = cidx * 64000;               // 4,096,000 chunks / 64
            for (int j = tid; j < 64000; j += 256) {
                int i = base + j;
                f32x4 v0 = __builtin_nontemporal_load(
                    reinterpret_cast<const f32x4*>(fc2w + (size_t)i * 8));
                f32x4 v1 = __builtin_nontemporal_load(
                    reinterpret_cast<const f32x4*>(fc2w + (size_t)i * 8 + 4));
                us8 c = {f2bf(v0[0]), f2bf(v0[1]), f2bf(v0[2]), f2bf(v0[3]),
                         f2bf(v1[0]), f2bf(v1[1]), f2bf(v1[2]), f2bf(v1[3])};
                __builtin_nontemporal_store(c,
                    reinterpret_cast<us8*>(fc2w_bf + (size_t)i * 8));
            }
        }
        return;
    }

    __shared__ __align__(16) us8 WB[8192];   // 128 KB
    __shared__ float red2[32 * 132];
    __shared__ float csh[512];

    const int lane = tid & 63;
    const int w    = tid >> 6;
    const int n    = lane & 31;
    const int kh   = lane >> 5;
    const int role = bid >> 6;        // 0=A, 1=C, 2=B
    const int lb   = bid & 63;
    const int j0   = lb * 16;
    const int b    = tid >> 3;
    const int jj   = tid & 7;

    unsigned short* hb0 = hbf;            // 4 x 32768
    unsigned short* hb1 = hbf + 131072;   // 2 x 32768

    {
        const float* Wsrc = (role == 0) ? Whh0 : (role == 1 ? Wih1 : Whh1);
        const int g = n >> 3, cj = n & 7;
#pragma unroll
        for (int T = 0; T < 2; ++T) {
            const float* wrow = Wsrc + (size_t)(g * HID + j0 + T * 8 + cj) * HID;
#pragma unroll
            for (int f = 0; f < 16; ++f) {
                int k = w * 256 + f * 16 + kh * 8;
                float4 v0 = *reinterpret_cast<const float4*>(wrow + k);
                float4 v1 = *reinterpret_cast<const float4*>(wrow + k + 4);
                WB[((T * 4 + w) * 16 + f) * 64 + lane] =
                    (us8){f2bf(v0.x), f2bf(v0.y), f2bf(v0.z), f2bf(v0.w),
                          f2bf(v1.x), f2bf(v1.y), f2bf(v1.z), f2bf(v1.w)};
            }
        }
    }

    float gp[2][4] = {};
    float bb[2][4] = {};
    if (role == 0) {
#pragma unroll
        for (int T = 0; T < 2; ++T) {
            csh[T * 256 + tid] = c0all[b * HID + j0 + T * 8 + jj];
#pragma unroll
            for (int g = 0; g < 4; ++g)
                gp[T][g] = gpre0[(size_t)b * 4096 + g * HID + j0 + T * 8 + jj];
        }
#pragma unroll
        for (int q = 0; q < 2; ++q) {
            int e = lb * 512 + q * 256 + tid;
            unsigned int hv = f2bf(h0all[((e >> 3) & 31) * HID + (e >> 8) * 8 + (e & 7)]);
            GST_U16_SC(hb0 + e, hv);
        }
    } else if (role == 2) {
#pragma unroll
        for (int T = 0; T < 2; ++T) {
            csh[T * 256 + tid] = c0all[32768 + b * HID + j0 + T * 8 + jj];
#pragma unroll
            for (int g = 0; g < 4; ++g)
                bb[T][g] = bih1[g * HID + j0 + T * 8 + jj] + bhh1[g * HID + j0 + T * 8 + jj];
        }
#pragma unroll
        for (int q = 0; q < 2; ++q) {
            int e = lb * 512 + q * 256 + tid;
            unsigned int hv = f2bf(h0all[32768 + ((e >> 3) & 31) * HID + (e >> 8) * 8 + (e & 7)]);
            GST_U16_SC(hb1 + 32768 + e, hv);
        }
    }

    WAIT_VM0();
    __syncthreads();
    if (tid == 0)
        __hip_atomic_store(&flags[bid * 32], 1, __ATOMIC_RELAXED, __HIP_MEMORY_SCOPE_AGENT);

    for (int p = 0; p <= 65; ++p) {
        {
            int g1, t1, g2, t2;
            if (role == 0)      { g1 = 0;   t1 = p + 1; g2 = 64;  t2 = p - 1; }
            else if (role == 1) { g1 = 0;   t1 = p + 1; g2 = 128; t2 = p - 1; }
            else                { g1 = 64;  t1 = p + 1; g2 = 128; t2 = p + 1; }
            if (tid < 64)        poll_group(flags, g1, t1);
            else if (tid < 128)  poll_group(flags, g2, t2);
            __syncthreads();
        }
        const bool active = (role == 0) ? (p <= 63)
                          : (role == 1) ? (p >= 1 && p <= 64)
                                        : (p >= 2);
        if (active) {
            const int t = p - role;
            f32x4 pv4[2];
            if (role == 2) {
                const float* pb = part + (size_t)((p - 2) & 3) * 131072 + lb * 2048 + tid * 4;
                GLD_F32X4_SC(pv4[0], pb);
                GLD_F32X4_SC(pv4[1], pb + 1024);
            }
            const unsigned short* hsrc = (role == 2)
                ? hb1 + ((p + 1) & 1) * 32768
                : hb0 + (p & 3) * 32768;
            const unsigned short* hr = hsrc + (size_t)w * 8192 + lane * 8;
            us8 aF[16];
#pragma unroll
            for (int f = 0; f < 16; ++f)
                GLD_US8_SC(aF[f], hr + f * 512);
            WAIT_VM0();
            __builtin_amdgcn_sched_barrier(0);

            f32x16 acc0 = {}, acc1 = {};
#pragma unroll
            for (int f = 0; f < 16; ++f)
                acc0 = __builtin_amdgcn_mfma_f32_32x32x16_bf16(
                    __builtin_bit_cast(bf16x8, aF[f]),
                    __builtin_bit_cast(bf16x8, WB[((0 * 4 + w) * 16 + f) * 64 + lane]),
                    acc0, 0, 0, 0);
#pragma unroll
            for (int f = 0; f < 16; ++f)
                acc1 = __builtin_amdgcn_mfma_f32_32x32x16_bf16(
                    __builtin_bit_cast(bf16x8, aF[f]),
                    __builtin_bit_cast(bf16x8, WB[((1 * 4 + w) * 16 + f) * 64 + lane]),
                    acc1, 0, 0, 0);

#pragma unroll
            for (int T = 0; T < 2; ++T) {
                if (T == 1) __syncthreads();
#pragma unroll
                for (int r = 0; r < 16; ++r) {
                    int m = (r & 3) + 8 * (r >> 2) + 4 * kh;
                    red2[m * 132 + w * 32 + n] = (T == 0) ? acc0[r] : acc1[r];
                }
                __syncthreads();
                float s0, s1, s2, s3;
                {
                    const float* rr = &red2[b * 132 + jj];
                    s0 = rr[0]  + rr[32]  + rr[64]  + rr[96];
                    s1 = rr[8]  + rr[40]  + rr[72]  + rr[104];
                    s2 = rr[16] + rr[48]  + rr[80]  + rr[112];
                    s3 = rr[24] + rr[56]  + rr[88]  + rr[120];
                }
                const int col = j0 + T * 8 + jj;
                const int he  = (lb * 2 + T) * 256 + tid;
                if (role == 1) {
                    float* pdst = part + (size_t)((p - 1) & 3) * 131072 + lb * 2048
                                + T * 1024 + tid * 4;
                    f32x4 sv4 = {s0, s1, s2, s3};
                    GST_F32X4_SC(pdst, sv4);
                } else {
                    if (role == 0) { s0 += gp[T][0]; s1 += gp[T][1]; s2 += gp[T][2]; s3 += gp[T][3]; }
                    else { s0 += pv4[T][0] + bb[T][0]; s1 += pv4[T][1] + bb[T][1];
                           s2 += pv4[T][2] + bb[T][2]; s3 += pv4[T][3] + bb[T][3]; }
                    float ig = 1.f / (1.f + expf(-s0));
                    float fg = 1.f / (1.f + expf(-s1));
                    float gg = tanhf(s2);
                    float og = 1.f / (1.f + expf(-s3));
                    float cv = fg * csh[T * 256 + tid] + ig * gg;
                    csh[T * 256 + tid] = cv;
                    float h = og * tanhf(cv);
                    unsigned int hv = f2bf(h);
                    if (role == 0) {
                        GST_U16_SC(hb0 + ((p + 1) & 3) * 32768 + he, hv);
                        if (t == T_STEPS - 1) { hn[b * HID + col] = h; cn[b * HID + col] = cv; }
                    } else {
                        __builtin_nontemporal_store(h, &y1o[(size_t)t * 32768 + b * HID + col]);
                        fin_bf[(size_t)(t * BATCH + b) * 2048 + 1024 + col] = f2bf(h);
                        if (t == T_STEPS - 1) {
                            hn[32768 + b * HID + col] = h;
                            cn[32768 + b * HID + col] = cv;
                        } else {
                            GST_U16_SC(hb1 + (p & 1) * 32768 + he, hv);
                        }
                    }
                }
            }
        }
        if (p < 65) {
            WAIT_VM0();
            __syncthreads();
            if (tid == 0)
                __hip_atomic_store(&flags[bid * 32], p + 2,
                                   __ATOMIC_RELAXED, __HIP_MEMORY_SCOPE_AGENT);
            if (role == 0 && p + 1 <= 63) {
                const float* gsrc = gpre0 + (size_t)((p + 1) * BATCH + b) * 4096 + j0 + jj;
#pragma unroll
                for (int T = 0; T < 2; ++T)
#pragma unroll
                    for (int g = 0; g < 4; ++g)
                        gp[T][g] = gsrc[g * HID + T * 8];
            }
        }
    }
}

// ---------------------------------------------------------------------------
// Fused attention v4 (verified round 14).
// ---------------------------------------------------------------------------
__global__ __launch_bounds__(256) void attn_fused4(
    const float* __restrict__ y1, const float* __restrict__ enc,
    const float* __restrict__ hidden1, const float* __restrict__ aw2,
    const float* __restrict__ ab2, const int* __restrict__ lengths,
    float* __restrict__ ctx, unsigned short* __restrict__ fin_bf)
{
    __shared__ __align__(16) float yl[4][1024];
    __shared__ float sv[4][104];
    __shared__ float av[4][104];
    __shared__ float p4[4];
    __shared__ int   win4[4];
    __shared__ int   winls;
    const int blk  = blockIdx.x;
    const int b    = blk >> 4;
    const int t0   = (blk & 15) * 4;
    const int tid  = threadIdx.x;
    const int wv   = tid >> 6;
    const int lane = tid & 63;
    const int len  = lengths[b];

    for (int i = tid; i < 4096; i += 256) {
        int r = i >> 10, h = i & 1023;
        yl[r][h] = y1[(size_t)((t0 + r) * BATCH + b) * HID + h];
    }

    {
        int row = (t0 + wv) * BATCH + b;
        float s = 0.f;
        for (int i = lane; i < 512; i += 64) s += hidden1[(size_t)row * 512 + i] * aw2[i];
        for (int off = 32; off > 0; off >>= 1) s += __shfl_down(s, off);
        if (lane == 0) {
            float sig = 1.f / (1.f + expf(-(s + ab2[0])));
            float lf = (float)len;
            p4[wv] = (float)WSZ_ + lf * sig;
            win4[wv] = (int)rintf(lf * sig);
        }
        if (wv == 0) {
            int rowl = (T_STEPS - 1) * BATCH + b;
            float s2 = 0.f;
            for (int i = lane; i < 512; i += 64) s2 += hidden1[(size_t)rowl * 512 + i] * aw2[i];
            for (int off = 32; off > 0; off >>= 1) s2 += __shfl_down(s2, off);
            if (lane == 0) {
                float sig = 1.f / (1.f + expf(-(s2 + ab2[0])));
                winls = (int)rintf((float)len * sig);
            }
        }
    }
    __syncthreads();
    const int wl = winls;

    if (tid < WLEN_) {
        const float4* s4p = reinterpret_cast<const float4*>(
            enc + ((size_t)(wl + tid) * BATCH + b) * HID);
        const float4* y0 = reinterpret_cast<const float4*>(yl[0]);
        const float4* y1p = reinterpret_cast<const float4*>(yl[1]);
        const float4* y2 = reinterpret_cast<const float4*>(yl[2]);
        const float4* y3 = reinterpret_cast<const float4*>(yl[3]);
        float a0 = 0.f, a1 = 0.f, a2 = 0.f, a3 = 0.f;
        for (int q = 0; q < 256; ++q) {
            float4 a = s4p[q];
            float4 v0 = y0[q];  a0 += a.x * v0.x + a.y * v0.y + a.z * v0.z + a.w * v0.w;
            float4 v1 = y1p[q]; a1 += a.x * v1.x + a.y * v1.y + a.z * v1.z + a.w * v1.w;
            float4 v2 = y2[q];  a2 += a.x * v2.x + a.y * v2.y + a.z * v2.z + a.w * v2.w;
            float4 v3 = y3[q];  a3 += a.x * v3.x + a.y * v3.y + a.z * v3.z + a.w * v3.w;
        }
        float accs[4] = {a0, a1, a2, a3};
#pragma unroll
        for (int r = 0; r < 4; ++r) {
            bool lo = tid < (WSZ_ - win4[r]);
            bool hi = tid >= (len + WSZ_ - win4[r]);
            sv[r][tid] = (lo || hi) ? 1e-14f : accs[r];
        }
    }
    __syncthreads();

    if (tid < WLEN_) {
#pragma unroll
        for (int r = 0; r < 4; ++r) {
            float mx = -1e30f;
            for (int w = 0; w < WLEN_; ++w) mx = fmaxf(mx, sv[r][w]);
            float sum = 0.f;
            for (int w = 0; w < WLEN_; ++w) sum += expf(sv[r][w] - mx);
            float e = expf(sv[r][tid] - mx) / sum;
            float d = (float)(win4[r] + tid) - p4[r];
            av[r][tid] = e * expf(-(d * d) / 1250.f);
        }
    }
    __syncthreads();

    {
        const int h0 = tid * 4;
        float ac[4][4] = {};
        for (int w = 0; w < WLEN_; ++w) {
            float4 s = *reinterpret_cast<const float4*>(
                enc + ((size_t)(wl + w) * BATCH + b) * HID + h0);
#pragma unroll
            for (int r = 0; r < 4; ++r) {
                float a = av[r][w];
                ac[r][0] += a * s.x; ac[r][1] += a * s.y;
                ac[r][2] += a * s.z; ac[r][3] += a * s.w;
            }
        }
#pragma unroll
        for (int r = 0; r < 4; ++r) {
            size_t row = (size_t)(t0 + r) * BATCH + b;
#pragma unroll
            for (int j = 0; j < 4; ++j) {
                ctx[row * HID + h0 + j] = ac[r][j];
                fin_bf[row * 2048 + h0 + j] = f2bf(ac[r][j]);
            }
        }
    }
}

// ---------------------------------------------------------------------------
__global__ void cvt_bf16_kernel(const float* __restrict__ src,
                                unsigned short* __restrict__ dst, int n8)
{
    for (int i = blockIdx.x * blockDim.x + threadIdx.x; i < n8;
         i += gridDim.x * blockDim.x) {
        float4 v0 = *reinterpret_cast<const float4*>(src + (size_t)i * 8);
        float4 v1 = *reinterpret_cast<const float4*>(src + (size_t)i * 8 + 4);
        us8 c = {f2bf(v0.x), f2bf(v0.y), f2bf(v0.z), f2bf(v0.w),
                 f2bf(v1.x), f2bf(v1.y), f2bf(v1.z), f2bf(v1.w)};
        *reinterpret_cast<us8*>(dst + (size_t)i * 8) = c;
    }
}

// ---------------------------------------------------------------------------
extern "C" void kernel_launch(void* const* d_in, const int* in_sizes, int n_in,
                              void* d_out, int out_size, void* d_ws, size_t ws_size,
                              hipStream_t stream)
{
    const float* enc   = (const float*)d_in[0];
    const float* ctxin = (const float*)d_in[1];
    const float* h0    = (const float*)d_in[2];
    const float* c0    = (const float*)d_in[3];
    const float* emb   = (const float*)d_in[4];
    const float* aw1   = (const float*)d_in[5];
    const float* ab1   = (const float*)d_in[6];
    const float* aw2   = (const float*)d_in[7];
    const float* ab2   = (const float*)d_in[8];
    const float* Wih0  = (const float*)d_in[9];
    const float* Whh0  = (const float*)d_in[10];
    const float* bih0  = (const float*)d_in[11];
    const float* bhh0  = (const float*)d_in[12];
    const float* Wih1  = (const float*)d_in[13];
    const float* Whh1  = (const float*)d_in[14];
    const float* bih1  = (const float*)d_in[15];
    const float* bhh1  = (const float*)d_in[16];
    const float* fc1w  = (const float*)d_in[17];
    const float* fc1b  = (const float*)d_in[18];
    const float* fc2w  = (const float*)d_in[19];
    const float* fc2b  = (const float*)d_in[20];
    const int*   tw    = (const int*)d_in[21];
    const int*   lens  = (const int*)d_in[22];

    float* ws = (float*)d_ws;
    float*          buf_gates = ws;                                   // gpre0
    unsigned short* x_bf      = (unsigned short*)(ws + 8388608);
    float*          buf_part  = ws + 8388608;                         // alias (4 slots)
    unsigned short* Wih0_bf   = (unsigned short*)(ws + 10485760);
    float*          buf_y1    = ws + 16384000;
    unsigned short* buf_hbf   = (unsigned short*)(ws + 18481152);
    int*            buf_flags = (int*)(ws + 18579456);
    float*          buf_hidden1 = ws + 18587904;
    unsigned short* fin_bf    = (unsigned short*)(ws + 22917376);
    unsigned short* fc1w_bf   = (unsigned short*)(ws + 25014528);
    unsigned short* fc1out_bf = (unsigned short*)(ws + 26063104);

    const size_t fold_end_bytes = (size_t)(27111680 + 8192000) * 4;
    const int cvtfc2 = (ws_size >= fold_end_bytes) ? 1 : 0;
    unsigned short* fc2w_bf = cvtfc2 ? (unsigned short*)(ws + 27111680)
                                     : (unsigned short*)ws;   // post-LSTM alias

    float* out   = (float*)d_out;
    float* out_hn  = out + Y_SZ;
    float* out_cn  = out + Y_SZ + HN_SZ;
    float* out_ctx = out + CTX_OFF;

    // 0. fused prep
    prep_kernel<<<3585, 256, 0, stream>>>(Wih0, Wih0_bf, fc1w, fc1w_bf,
                                          emb, ctxin, tw, x_bf, buf_flags);

    // 1. gates0_pre = x @ Wih0^T + bih0 + bhh0
    gemm_lds_bt<<<512, 256, 0, stream>>>(
        x_bf, Wih0_bf, bih0, bhh0, buf_gates, nullptr, 2048, 4096, 2048, 0, 0);

    // 2. Both LSTM layers + nontemporal D-group fc2w convert (grid 256)
    lstm_fused3<<<3 * LBLK + 64, 256, 0, stream>>>(
        buf_gates, Whh0, Wih1, Whh1, bih1, bhh1, h0, c0,
        buf_y1, fin_bf, out_hn, out_cn, buf_hbf, buf_part, buf_flags,
        fc2w, fc2w_bf, cvtfc2);

    // 3. fc2 weight convert fallback (only if workspace was too small)
    if (!cvtfc2)
        cvt_bf16_kernel<<<2048, 256, 0, stream>>>(fc2w, fc2w_bf, VOCAB * HID / 8);

    // 4. Attention: hidden1 (fp32 exact) then fused p/win+QK+softmax+PV
    gemm_bt<<<dim3(512 / 64, 2048 / 128), 256, 0, stream>>>(
        buf_y1, aw1, ab1, nullptr, buf_hidden1, 2048, 512, 1024, 2 /*tanh*/);
    attn_fused4<<<512, 256, 0, stream>>>(buf_y1, enc, buf_hidden1, aw2, ab2, lens,
                                         out_ctx, fin_bf);

    // 5. fc1 = relu([ctx, y1] @ fc1_w^T + fc1_b) -> bf16
    gemm_lds_bt<<<128, 256, 0, stream>>>(
        fin_bf, fc1w_bf, fc1b, nullptr, nullptr, fc1out_bf, 2048, 1024, 2048, 1, 0);

    // 6. fc2 -> fp32 d_out (nontemporal)
    gemm_lds_bt<<<4000, 256, 0, stream>>>(
        fc1out_bf, fc2w_bf, fc2b, nullptr, out, nullptr, 2048, VOCAB, 1024, 0, 1);
}

// Round 19
// 887.520 us; speedup vs baseline: 1.0820x; 1.0407x over previous
//
#include <hip/hip_runtime.h>
#include <hip/hip_bf16.h>

// Problem constants
#define T_STEPS 64
#define BATCH   32
#define HID     1024
#define VOCAB   32000
#define WLEN_   101
#define WSZ_    50
#define SENC    229
#define LBLK    64      // blocks per LSTM role; grid = 3*LBLK + 64 cvt = 256

static const size_t Y_SZ   = (size_t)T_STEPS * BATCH * VOCAB;   // 65,536,000
static const size_t HN_SZ  = (size_t)2 * BATCH * HID;           // 65,536
static const size_t CTX_OFF = Y_SZ + 2 * HN_SZ;                 // y + h_n + c_n

typedef __attribute__((ext_vector_type(8)))  unsigned short us8;
typedef __attribute__((ext_vector_type(4)))  unsigned short us4;
typedef __attribute__((ext_vector_type(8)))  __bf16 bf16x8;
typedef __attribute__((ext_vector_type(4)))  float f32x4;
typedef __attribute__((ext_vector_type(16))) float f32x16;

static __device__ inline unsigned short f2bf(float x) {
    __hip_bfloat16 b = __float2bfloat16(x);
    return __builtin_bit_cast(unsigned short, b);
}

// Coherence-point (LLC) accesses for the LSTM cross-block exchange.
#define GLD_US8_SC(dst, ptr) \
    asm volatile("global_load_dwordx4 %0, %1, off sc0 sc1" : "=v"(dst) : "v"(ptr) : "memory")
#define GLD_F32X4_SC(dst, ptr) \
    asm volatile("global_load_dwordx4 %0, %1, off sc0 sc1" : "=v"(dst) : "v"(ptr) : "memory")
#define GST_U16_SC(ptr, val) \
    asm volatile("global_store_short %0, %1, off sc0 sc1" :: "v"(ptr), "v"(val) : "memory")
#define GST_F32X4_SC(ptr, val) \
    asm volatile("global_store_dwordx4 %0, %1, off sc0 sc1" :: "v"(ptr), "v"(val) : "memory")
#define WAIT_VM0() asm volatile("s_waitcnt vmcnt(0)" ::: "memory")

// ---------------------------------------------------------------------------
// fp32 GEMM (attn-proj path only — keeps window indices exact)
// ---------------------------------------------------------------------------
__global__ __launch_bounds__(256) void gemm_bt(
    const float* __restrict__ A, const float* __restrict__ W,
    const float* __restrict__ b1, const float* __restrict__ b2,
    float* __restrict__ out, int M, int N, int K, int act)
{
    __shared__ __align__(16) float As[16 * 132];
    __shared__ __align__(16) float Ws[16 * 68];
    const int tid  = threadIdx.x;
    const int col0 = blockIdx.x * 64;
    const int row0 = blockIdx.y * 128;
    const int ty   = tid >> 4;
    const int tx   = tid & 15;

    float acc[8][4];
#pragma unroll
    for (int i = 0; i < 8; ++i)
#pragma unroll
        for (int j = 0; j < 4; ++j) acc[i][j] = 0.f;

    for (int k0 = 0; k0 < K; k0 += 16) {
#pragma unroll
        for (int li = 0; li < 2; ++li) {
            int f  = tid + li * 256;
            int r  = f >> 2;
            int kq = (f & 3) << 2;
            float4 v = *reinterpret_cast<const float4*>(A + (size_t)(row0 + r) * K + k0 + kq);
            As[(kq + 0) * 132 + r] = v.x;
            As[(kq + 1) * 132 + r] = v.y;
            As[(kq + 2) * 132 + r] = v.z;
            As[(kq + 3) * 132 + r] = v.w;
        }
        {
            int n  = tid >> 2;
            int kq = (tid & 3) << 2;
            float4 v = *reinterpret_cast<const float4*>(W + (size_t)(col0 + n) * K + k0 + kq);
            Ws[(kq + 0) * 68 + n] = v.x;
            Ws[(kq + 1) * 68 + n] = v.y;
            Ws[(kq + 2) * 68 + n] = v.z;
            Ws[(kq + 3) * 68 + n] = v.w;
        }
        __syncthreads();
#pragma unroll
        for (int k = 0; k < 16; ++k) {
            const float4 a0 = *reinterpret_cast<const float4*>(&As[k * 132 + ty * 8]);
            const float4 a1 = *reinterpret_cast<const float4*>(&As[k * 132 + ty * 8 + 4]);
            const float4 b0 = *reinterpret_cast<const float4*>(&Ws[k * 68 + tx * 4]);
            float av[8] = {a0.x, a0.y, a0.z, a0.w, a1.x, a1.y, a1.z, a1.w};
            float bv[4] = {b0.x, b0.y, b0.z, b0.w};
#pragma unroll
            for (int i = 0; i < 8; ++i)
#pragma unroll
                for (int j = 0; j < 4; ++j) acc[i][j] = fmaf(av[i], bv[j], acc[i][j]);
        }
        __syncthreads();
    }

#pragma unroll
    for (int j = 0; j < 4; ++j) {
        int n = col0 + tx * 4 + j;
        float bias = 0.f;
        if (b1) bias += b1[n];
        if (b2) bias += b2[n];
#pragma unroll
        for (int i = 0; i < 8; ++i) {
            float v = acc[i][j] + bias;
            if (act == 1) v = fmaxf(v, 0.f);
            else if (act == 2) v = tanhf(v);
            out[(size_t)(row0 + ty * 8 + i) * N + n] = v;
        }
    }
}

// ---------------------------------------------------------------------------
// bf16 MFMA GEMM, m97-style (verified rounds 8-18). This round: LDS-transpose
// epilogue — bias/relu in-register, C staged per 64-row half into [64][132]
// fp32 LDS (aliasing dead As/Ws), then fully-coalesced float4 stores.
// Same values, same rounding — bit-identical outputs.
// ---------------------------------------------------------------------------
__global__ __launch_bounds__(256) void gemm_lds_bt(
    const unsigned short* __restrict__ A, const unsigned short* __restrict__ W,
    const float* __restrict__ b1, const float* __restrict__ b2,
    float* __restrict__ out, unsigned short* __restrict__ out_bf,
    int M, int N, int K, int relu, int ntout)
{
    __shared__ __align__(16) unsigned char smem[33792];   // max(As+Ws 32KB, Cs 33KB)
    unsigned short* As = reinterpret_cast<unsigned short*>(smem);          // [8192]
    unsigned short* Ws = reinterpret_cast<unsigned short*>(smem) + 8192;   // [8192]
    float*          Cs = reinterpret_cast<float*>(smem);                   // [64][132]

    const int tid  = threadIdx.x;
    const int lane = tid & 63;
    const int wave = tid >> 6;

    const int nwg = gridDim.x;
    const int bid = blockIdx.x;
    const int q = nwg >> 3, r8 = nwg & 7;
    const int xcd = bid & 7, sidx = bid >> 3;
    const int wgid = (xcd < r8 ? xcd * (q + 1) : r8 * (q + 1) + (xcd - r8) * q) + sidx;
    const int mt = M >> 7;
    const int row0 = (wgid % mt) << 7;
    const int col0 = (wgid / mt) << 7;

    const int m0   = (wave >> 1) * 64;
    const int n0   = (wave & 1) * 64;
    const int lrow = lane & 15;
    const int kc   = lane >> 4;

    f32x4 acc[4][4];
#pragma unroll
    for (int i = 0; i < 4; ++i)
#pragma unroll
        for (int j = 0; j < 4; ++j) acc[i][j] = (f32x4){0.f, 0.f, 0.f, 0.f};

    const bool isA = (wave < 2);
    const int  lw  = wave & 1;
    const unsigned short* gbase = isA ? (A + (size_t)row0 * K) : (W + (size_t)col0 * K);
    unsigned short* lbase = isA ? As : Ws;

    for (int k0 = 0; k0 < K; k0 += 64) {
#pragma unroll
        for (int i = 0; i < 8; ++i) {
            const int c    = lw * 512 + i * 64 + lane;
            const int row  = c >> 3;
            const int slot = c & 7;
            const unsigned short* src =
                gbase + (size_t)row * K + k0 + ((slot ^ (row & 7)) << 3);
            __builtin_amdgcn_global_load_lds(
                (const __attribute__((address_space(1))) void*)src,
                (__attribute__((address_space(3))) void*)(lbase + (size_t)(lw * 512 + i * 64) * 8),
                16, 0, 0);
        }
        __syncthreads();
#pragma unroll
        for (int ss = 0; ss < 2; ++ss) {
            us8 a[4], b[4];
#pragma unroll
            for (int f = 0; f < 4; ++f) {
                const int ar = m0 + f * 16 + lrow;
                const int as = (ss * 4 + kc) ^ (ar & 7);
                a[f] = *reinterpret_cast<const us8*>(&As[(ar * 8 + as) * 8]);
                const int br = n0 + f * 16 + lrow;
                const int bs = (ss * 4 + kc) ^ (br & 7);
                b[f] = *reinterpret_cast<const us8*>(&Ws[(br * 8 + bs) * 8]);
            }
#pragma unroll
            for (int fi = 0; fi < 4; ++fi)
#pragma unroll
                for (int fj = 0; fj < 4; ++fj)
                    acc[fi][fj] = __builtin_amdgcn_mfma_f32_16x16x32_bf16(
                        __builtin_bit_cast(bf16x8, a[fi]),
                        __builtin_bit_cast(bf16x8, b[fj]),
                        acc[fi][fj], 0, 0, 0);
        }
        __syncthreads();
    }

    // ---- bias/relu in-register (same values/order as before) ----
#pragma unroll
    for (int fj = 0; fj < 4; ++fj) {
        const int cN = col0 + n0 + fj * 16 + lrow;
        float bv = 0.f;
        if (b1) bv += b1[cN];
        if (b2) bv += b2[cN];
#pragma unroll
        for (int fi = 0; fi < 4; ++fi)
#pragma unroll
            for (int j = 0; j < 4; ++j) {
                float v = acc[fi][fj][j] + bv;
                if (relu) v = fmaxf(v, 0.f);
                acc[fi][fj][j] = v;
            }
    }

    // ---- LDS transpose + coalesced stores, one 64-row half at a time ----
    const int mh = wave >> 1;        // this wave's row-half (m0 == mh*64)
#pragma unroll
    for (int h = 0; h < 2; ++h) {
        __syncthreads();             // previous half's reads (or k-loop) done
        if (mh == h) {
#pragma unroll
            for (int fi = 0; fi < 4; ++fi)
#pragma unroll
                for (int fj = 0; fj < 4; ++fj) {
                    const int c = n0 + fj * 16 + lrow;            // 0..127
#pragma unroll
                    for (int j = 0; j < 4; ++j)
                        Cs[(fi * 16 + (lane >> 4) * 4 + j) * 132 + c] = acc[fi][fj][j];
                }
        }
        __syncthreads();
#pragma unroll
        for (int i = 0; i < 8; ++i) {
            const int idx = i * 256 + tid;                        // 0..2047
            const int r = idx >> 5, c4 = idx & 31;
            f32x4 v = *reinterpret_cast<const f32x4*>(&Cs[r * 132 + c4 * 4]);
            const size_t go = (size_t)(row0 + h * 64 + r) * N + col0 + c4 * 4;
            if (out) {
                if (ntout) __builtin_nontemporal_store(v, reinterpret_cast<f32x4*>(&out[go]));
                else       *reinterpret_cast<f32x4*>(&out[go]) = v;
            }
            if (out_bf) {
                us4 pv = {f2bf(v[0]), f2bf(v[1]), f2bf(v[2]), f2bf(v[3])};
                *reinterpret_cast<us4*>(&out_bf[go]) = pv;
            }
        }
    }
}

// ---------------------------------------------------------------------------
// Fused prep: Wih0->bf16, fc1w->bf16, embed+concat->bf16, zero flags.
// ---------------------------------------------------------------------------
__global__ void prep_kernel(const float* __restrict__ Wih0, unsigned short* __restrict__ Wih0_bf,
                            const float* __restrict__ fc1w, unsigned short* __restrict__ fc1w_bf,
                            const float* __restrict__ emb, const float* __restrict__ ctxin,
                            const int* __restrict__ tw, unsigned short* __restrict__ x_bf,
                            int* __restrict__ flags)
{
    const int bid = blockIdx.x, tid = threadIdx.x;
    if (bid < 2048) {
#pragma unroll
        for (int k = 0; k < 2; ++k) {
            int i = bid * 256 + tid + k * 524288;
            float4 v0 = *reinterpret_cast<const float4*>(Wih0 + (size_t)i * 8);
            float4 v1 = *reinterpret_cast<const float4*>(Wih0 + (size_t)i * 8 + 4);
            us8 c = {f2bf(v0.x), f2bf(v0.y), f2bf(v0.z), f2bf(v0.w),
                     f2bf(v1.x), f2bf(v1.y), f2bf(v1.z), f2bf(v1.w)};
            *reinterpret_cast<us8*>(Wih0_bf + (size_t)i * 8) = c;
        }
    } else if (bid < 3072) {
        int i = (bid - 2048) * 256 + tid;
        float4 v0 = *reinterpret_cast<const float4*>(fc1w + (size_t)i * 8);
        float4 v1 = *reinterpret_cast<const float4*>(fc1w + (size_t)i * 8 + 4);
        us8 c = {f2bf(v0.x), f2bf(v0.y), f2bf(v0.z), f2bf(v0.w),
                 f2bf(v1.x), f2bf(v1.y), f2bf(v1.z), f2bf(v1.w)};
        *reinterpret_cast<us8*>(fc1w_bf + (size_t)i * 8) = c;
    } else if (bid < 3584) {
#pragma unroll
        for (int k = 0; k < 4; ++k) {
            int idx = (bid - 3072) * 256 + tid + k * 131072;
            int row = idx >> 8;
            int c8  = idx & 255;
            const float* src = (c8 < 128)
                ? emb + (size_t)tw[row] * HID + c8 * 8
                : ctxin + (size_t)row * HID + (c8 - 128) * 8;
            float4 v0 = *reinterpret_cast<const float4*>(src);
            float4 v1 = *reinterpret_cast<const float4*>(src + 4);
            us8 c = {f2bf(v0.x), f2bf(v0.y), f2bf(v0.z), f2bf(v0.w),
                     f2bf(v1.x), f2bf(v1.y), f2bf(v1.z), f2bf(v1.w)};
            *reinterpret_cast<us8*>(x_bf + (size_t)idx * 8) = c;
        }
    } else {
        for (int i = tid; i < 6400; i += 256) flags[i] = 0;
    }
}

// ---------------------------------------------------------------------------
// 1-hop scoped barrier (round-12 init-poll lesson applied).
// ---------------------------------------------------------------------------
static __device__ inline void poll_group(int* __restrict__ flags, int gbase, int target)
{
    if (target <= 0) return;
    const int lane = threadIdx.x & 63;
    int* fp = &flags[(gbase + lane) * 32];
    for (;;) {
        int f = __hip_atomic_load(fp, __ATOMIC_RELAXED, __HIP_MEMORY_SCOPE_AGENT);
        if (__all(f >= target)) break;
        __builtin_amdgcn_s_sleep(1);
    }
}

// ---------------------------------------------------------------------------
// 3-role fused persistent LSTM + throttled idle-CU D-group fc2w convert.
// ---------------------------------------------------------------------------
__global__ __launch_bounds__(256) void lstm_fused3(
    const float* __restrict__ gpre0,
    const float* __restrict__ Whh0, const float* __restrict__ Wih1,
    const float* __restrict__ Whh1,
    const float* __restrict__ bih1, const float* __restrict__ bhh1,
    const float* __restrict__ h0all, const float* __restrict__ c0all,
    float* __restrict__ y1o,
    unsigned short* __restrict__ fin_bf,
    float* __restrict__ hn, float* __restrict__ cn,
    unsigned short* __restrict__ hbf,
    float* __restrict__ part,
    int* __restrict__ flags,
    const float* __restrict__ fc2w, unsigned short* __restrict__ fc2w_bf,
    int cvtfc2)
{
    const int bid = blockIdx.x;
    const int tid = threadIdx.x;

    // ---- D-group: fc2w convert, nontemporal + throttled (s_sleep spreads the
    // 192MB stream over ~2x the time, reducing contention with LSTM phases) ----
    if (bid >= 3 * LBLK) {
        if (cvtfc2) {
            const int cidx = bid - 3 * LBLK;             // 0..63
            const int base = cidx * 64000;
            for (int j = tid; j < 64000; j += 256) {
                int i = base + j;
                f32x4 v0 = __builtin_nontemporal_load(
                    reinterpret_cast<const f32x4*>(fc2w + (size_t)i * 8));
                f32x4 v1 = __builtin_nontemporal_load(
                    reinterpret_cast<const f32x4*>(fc2w + (size_t)i * 8 + 4));
                us8 c = {f2bf(v0[0]), f2bf(v0[1]), f2bf(v0[2]), f2bf(v0[3]),
                         f2bf(v1[0]), f2bf(v1[1]), f2bf(v1[2]), f2bf(v1[3])};
                __builtin_nontemporal_store(c,
                    reinterpret_cast<us8*>(fc2w_bf + (size_t)i * 8));
                __builtin_amdgcn_s_sleep(16);
            }
        }
        return;
    }

    __shared__ __align__(16) us8 WB[8192];   // 128 KB
    __shared__ float red2[32 * 132];
    __shared__ float csh[512];

    const int lane = tid & 63;
    const int w    = tid >> 6;
    const int n    = lane & 31;
    const int kh   = lane >> 5;
    const int role = bid >> 6;        // 0=A, 1=C, 2=B
    const int lb   = bid & 63;
    const int j0   = lb * 16;
    const int b    = tid >> 3;
    const int jj   = tid & 7;

    unsigned short* hb0 = hbf;            // 4 x 32768
    unsigned short* hb1 = hbf + 131072;   // 2 x 32768

    {
        const float* Wsrc = (role == 0) ? Whh0 : (role == 1 ? Wih1 : Whh1);
        const int g = n >> 3, cj = n & 7;
#pragma unroll
        for (int T = 0; T < 2; ++T) {
            const float* wrow = Wsrc + (size_t)(g * HID + j0 + T * 8 + cj) * HID;
#pragma unroll
            for (int f = 0; f < 16; ++f) {
                int k = w * 256 + f * 16 + kh * 8;
                float4 v0 = *reinterpret_cast<const float4*>(wrow + k);
                float4 v1 = *reinterpret_cast<const float4*>(wrow + k + 4);
                WB[((T * 4 + w) * 16 + f) * 64 + lane] =
                    (us8){f2bf(v0.x), f2bf(v0.y), f2bf(v0.z), f2bf(v0.w),
                          f2bf(v1.x), f2bf(v1.y), f2bf(v1.z), f2bf(v1.w)};
            }
        }
    }

    float gp[2][4] = {};
    float bb[2][4] = {};
    if (role == 0) {
#pragma unroll
        for (int T = 0; T < 2; ++T) {
            csh[T * 256 + tid] = c0all[b * HID + j0 + T * 8 + jj];
#pragma unroll
            for (int g = 0; g < 4; ++g)
                gp[T][g] = gpre0[(size_t)b * 4096 + g * HID + j0 + T * 8 + jj];
        }
#pragma unroll
        for (int q = 0; q < 2; ++q) {
            int e = lb * 512 + q * 256 + tid;
            unsigned int hv = f2bf(h0all[((e >> 3) & 31) * HID + (e >> 8) * 8 + (e & 7)]);
            GST_U16_SC(hb0 + e, hv);
        }
    } else if (role == 2) {
#pragma unroll
        for (int T = 0; T < 2; ++T) {
            csh[T * 256 + tid] = c0all[32768 + b * HID + j0 + T * 8 + jj];
#pragma unroll
            for (int g = 0; g < 4; ++g)
                bb[T][g] = bih1[g * HID + j0 + T * 8 + jj] + bhh1[g * HID + j0 + T * 8 + jj];
        }
#pragma unroll
        for (int q = 0; q < 2; ++q) {
            int e = lb * 512 + q * 256 + tid;
            unsigned int hv = f2bf(h0all[32768 + ((e >> 3) & 31) * HID + (e >> 8) * 8 + (e & 7)]);
            GST_U16_SC(hb1 + 32768 + e, hv);
        }
    }

    WAIT_VM0();
    __syncthreads();
    if (tid == 0)
        __hip_atomic_store(&flags[bid * 32], 1, __ATOMIC_RELAXED, __HIP_MEMORY_SCOPE_AGENT);

    for (int p = 0; p <= 65; ++p) {
        {
            int g1, t1, g2, t2;
            if (role == 0)      { g1 = 0;   t1 = p + 1; g2 = 64;  t2 = p - 1; }
            else if (role == 1) { g1 = 0;   t1 = p + 1; g2 = 128; t2 = p - 1; }
            else                { g1 = 64;  t1 = p + 1; g2 = 128; t2 = p + 1; }
            if (tid < 64)        poll_group(flags, g1, t1);
            else if (tid < 128)  poll_group(flags, g2, t2);
            __syncthreads();
        }
        const bool active = (role == 0) ? (p <= 63)
                          : (role == 1) ? (p >= 1 && p <= 64)
                                        : (p >= 2);
        if (active) {
            const int t = p - role;
            f32x4 pv4[2];
            if (role == 2) {
                const float* pb = part + (size_t)((p - 2) & 3) * 131072 + lb * 2048 + tid * 4;
                GLD_F32X4_SC(pv4[0], pb);
                GLD_F32X4_SC(pv4[1], pb + 1024);
            }
            const unsigned short* hsrc = (role == 2)
                ? hb1 + ((p + 1) & 1) * 32768
                : hb0 + (p & 3) * 32768;
            const unsigned short* hr = hsrc + (size_t)w * 8192 + lane * 8;
            us8 aF[16];
#pragma unroll
            for (int f = 0; f < 16; ++f)
                GLD_US8_SC(aF[f], hr + f * 512);
            WAIT_VM0();
            __builtin_amdgcn_sched_barrier(0);

            f32x16 acc0 = {}, acc1 = {};
#pragma unroll
            for (int f = 0; f < 16; ++f)
                acc0 = __builtin_amdgcn_mfma_f32_32x32x16_bf16(
                    __builtin_bit_cast(bf16x8, aF[f]),
                    __builtin_bit_cast(bf16x8, WB[((0 * 4 + w) * 16 + f) * 64 + lane]),
                    acc0, 0, 0, 0);
#pragma unroll
            for (int f = 0; f < 16; ++f)
                acc1 = __builtin_amdgcn_mfma_f32_32x32x16_bf16(
                    __builtin_bit_cast(bf16x8, aF[f]),
                    __builtin_bit_cast(bf16x8, WB[((1 * 4 + w) * 16 + f) * 64 + lane]),
                    acc1, 0, 0, 0);

#pragma unroll
            for (int T = 0; T < 2; ++T) {
                if (T == 1) __syncthreads();
#pragma unroll
                for (int r = 0; r < 16; ++r) {
                    int m = (r & 3) + 8 * (r >> 2) + 4 * kh;
                    red2[m * 132 + w * 32 + n] = (T == 0) ? acc0[r] : acc1[r];
                }
                __syncthreads();
                float s0, s1, s2, s3;
                {
                    const float* rr = &red2[b * 132 + jj];
                    s0 = rr[0]  + rr[32]  + rr[64]  + rr[96];
                    s1 = rr[8]  + rr[40]  + rr[72]  + rr[104];
                    s2 = rr[16] + rr[48]  + rr[80]  + rr[112];
                    s3 = rr[24] + rr[56]  + rr[88]  + rr[120];
                }
                const int col = j0 + T * 8 + jj;
                const int he  = (lb * 2 + T) * 256 + tid;
                if (role == 1) {
                    float* pdst = part + (size_t)((p - 1) & 3) * 131072 + lb * 2048
                                + T * 1024 + tid * 4;
                    f32x4 sv4 = {s0, s1, s2, s3};
                    GST_F32X4_SC(pdst, sv4);
                } else {
                    if (role == 0) { s0 += gp[T][0]; s1 += gp[T][1]; s2 += gp[T][2]; s3 += gp[T][3]; }
                    else { s0 += pv4[T][0] + bb[T][0]; s1 += pv4[T][1] + bb[T][1];
                           s2 += pv4[T][2] + bb[T][2]; s3 += pv4[T][3] + bb[T][3]; }
                    float ig = 1.f / (1.f + expf(-s0));
                    float fg = 1.f / (1.f + expf(-s1));
                    float gg = tanhf(s2);
                    float og = 1.f / (1.f + expf(-s3));
                    float cv = fg * csh[T * 256 + tid] + ig * gg;
                    csh[T * 256 + tid] = cv;
                    float h = og * tanhf(cv);
                    unsigned int hv = f2bf(h);
                    if (role == 0) {
                        GST_U16_SC(hb0 + ((p + 1) & 3) * 32768 + he, hv);
                        if (t == T_STEPS - 1) { hn[b * HID + col] = h; cn[b * HID + col] = cv; }
                    } else {
                        __builtin_nontemporal_store(h, &y1o[(size_t)t * 32768 + b * HID + col]);
                        fin_bf[(size_t)(t * BATCH + b) * 2048 + 1024 + col] = f2bf(h);
                        if (t == T_STEPS - 1) {
                            hn[32768 + b * HID + col] = h;
                            cn[32768 + b * HID + col] = cv;
                        } else {
                            GST_U16_SC(hb1 + (p & 1) * 32768 + he, hv);
                        }
                    }
                }
            }
        }
        if (p < 65) {
            WAIT_VM0();
            __syncthreads();
            if (tid == 0)
                __hip_atomic_store(&flags[bid * 32], p + 2,
                                   __ATOMIC_RELAXED, __HIP_MEMORY_SCOPE_AGENT);
            if (role == 0 && p + 1 <= 63) {
                const float* gsrc = gpre0 + (size_t)((p + 1) * BATCH + b) * 4096 + j0 + jj;
#pragma unroll
                for (int T = 0; T < 2; ++T)
#pragma unroll
                    for (int g = 0; g < 4; ++g)
                        gp[T][g] = gsrc[g * HID + T * 8];
            }
        }
    }
}

// ---------------------------------------------------------------------------
// Fused attention v4 (verified round 14).
// ---------------------------------------------------------------------------
__global__ __launch_bounds__(256) void attn_fused4(
    const float* __restrict__ y1, const float* __restrict__ enc,
    const float* __restrict__ hidden1, const float* __restrict__ aw2,
    const float* __restrict__ ab2, const int* __restrict__ lengths,
    float* __restrict__ ctx, unsigned short* __restrict__ fin_bf)
{
    __shared__ __align__(16) float yl[4][1024];
    __shared__ float sv[4][104];
    __shared__ float av[4][104];
    __shared__ float p4[4];
    __shared__ int   win4[4];
    __shared__ int   winls;
    const int blk  = blockIdx.x;
    const int b    = blk >> 4;
    const int t0   = (blk & 15) * 4;
    const int tid  = threadIdx.x;
    const int wv   = tid >> 6;
    const int lane = tid & 63;
    const int len  = lengths[b];

    for (int i = tid; i < 4096; i += 256) {
        int r = i >> 10, h = i & 1023;
        yl[r][h] = y1[(size_t)((t0 + r) * BATCH + b) * HID + h];
    }

    {
        int row = (t0 + wv) * BATCH + b;
        float s = 0.f;
        for (int i = lane; i < 512; i += 64) s += hidden1[(size_t)row * 512 + i] * aw2[i];
        for (int off = 32; off > 0; off >>= 1) s += __shfl_down(s, off);
        if (lane == 0) {
            float sig = 1.f / (1.f + expf(-(s + ab2[0])));
            float lf = (float)len;
            p4[wv] = (float)WSZ_ + lf * sig;
            win4[wv] = (int)rintf(lf * sig);
        }
        if (wv == 0) {
            int rowl = (T_STEPS - 1) * BATCH + b;
            float s2 = 0.f;
            for (int i = lane; i < 512; i += 64) s2 += hidden1[(size_t)rowl * 512 + i] * aw2[i];
            for (int off = 32; off > 0; off >>= 1) s2 += __shfl_down(s2, off);
            if (lane == 0) {
                float sig = 1.f / (1.f + expf(-(s2 + ab2[0])));
                winls = (int)rintf((float)len * sig);
            }
        }
    }
    __syncthreads();
    const int wl = winls;

    if (tid < WLEN_) {
        const float4* s4p = reinterpret_cast<const float4*>(
            enc + ((size_t)(wl + tid) * BATCH + b) * HID);
        const float4* y0 = reinterpret_cast<const float4*>(yl[0]);
        const float4* y1p = reinterpret_cast<const float4*>(yl[1]);
        const float4* y2 = reinterpret_cast<const float4*>(yl[2]);
        const float4* y3 = reinterpret_cast<const float4*>(yl[3]);
        float a0 = 0.f, a1 = 0.f, a2 = 0.f, a3 = 0.f;
        for (int q = 0; q < 256; ++q) {
            float4 a = s4p[q];
            float4 v0 = y0[q];  a0 += a.x * v0.x + a.y * v0.y + a.z * v0.z + a.w * v0.w;
            float4 v1 = y1p[q]; a1 += a.x * v1.x + a.y * v1.y + a.z * v1.z + a.w * v1.w;
            float4 v2 = y2[q];  a2 += a.x * v2.x + a.y * v2.y + a.z * v2.z + a.w * v2.w;
            float4 v3 = y3[q];  a3 += a.x * v3.x + a.y * v3.y + a.z * v3.z + a.w * v3.w;
        }
        float accs[4] = {a0, a1, a2, a3};
#pragma unroll
        for (int r = 0; r < 4; ++r) {
            bool lo = tid < (WSZ_ - win4[r]);
            bool hi = tid >= (len + WSZ_ - win4[r]);
            sv[r][tid] = (lo || hi) ? 1e-14f : accs[r];
        }
    }
    __syncthreads();

    if (tid < WLEN_) {
#pragma unroll
        for (int r = 0; r < 4; ++r) {
            float mx = -1e30f;
            for (int w = 0; w < WLEN_; ++w) mx = fmaxf(mx, sv[r][w]);
            float sum = 0.f;
            for (int w = 0; w < WLEN_; ++w) sum += expf(sv[r][w] - mx);
            float e = expf(sv[r][tid] - mx) / sum;
            float d = (float)(win4[r] + tid) - p4[r];
            av[r][tid] = e * expf(-(d * d) / 1250.f);
        }
    }
    __syncthreads();

    {
        const int h0 = tid * 4;
        float ac[4][4] = {};
        for (int w = 0; w < WLEN_; ++w) {
            float4 s = *reinterpret_cast<const float4*>(
                enc + ((size_t)(wl + w) * BATCH + b) * HID + h0);
#pragma unroll
            for (int r = 0; r < 4; ++r) {
                float a = av[r][w];
                ac[r][0] += a * s.x; ac[r][1] += a * s.y;
                ac[r][2] += a * s.z; ac[r][3] += a * s.w;
            }
        }
#pragma unroll
        for (int r = 0; r < 4; ++r) {
            size_t row = (size_t)(t0 + r) * BATCH + b;
#pragma unroll
            for (int j = 0; j < 4; ++j) {
                ctx[row * HID + h0 + j] = ac[r][j];
                fin_bf[row * 2048 + h0 + j] = f2bf(ac[r][j]);
            }
        }
    }
}

// ---------------------------------------------------------------------------
__global__ void cvt_bf16_kernel(const float* __restrict__ src,
                                unsigned short* __restrict__ dst, int n8)
{
    for (int i = blockIdx.x * blockDim.x + threadIdx.x; i < n8;
         i += gridDim.x * blockDim.x) {
        float4 v0 = *reinterpret_cast<const float4*>(src + (size_t)i * 8);
        float4 v1 = *reinterpret_cast<const float4*>(src + (size_t)i * 8 + 4);
        us8 c = {f2bf(v0.x), f2bf(v0.y), f2bf(v0.z), f2bf(v0.w),
                 f2bf(v1.x), f2bf(v1.y), f2bf(v1.z), f2bf(v1.w)};
        *reinterpret_cast<us8*>(dst + (size_t)i * 8) = c;
    }
}

// ---------------------------------------------------------------------------
extern "C" void kernel_launch(void* const* d_in, const int* in_sizes, int n_in,
                              void* d_out, int out_size, void* d_ws, size_t ws_size,
                              hipStream_t stream)
{
    const float* enc   = (const float*)d_in[0];
    const float* ctxin = (const float*)d_in[1];
    const float* h0    = (const float*)d_in[2];
    const float* c0    = (const float*)d_in[3];
    const float* emb   = (const float*)d_in[4];
    const float* aw1   = (const float*)d_in[5];
    const float* ab1   = (const float*)d_in[6];
    const float* aw2   = (const float*)d_in[7];
    const float* ab2   = (const float*)d_in[8];
    const float* Wih0  = (const float*)d_in[9];
    const float* Whh0  = (const float*)d_in[10];
    const float* bih0  = (const float*)d_in[11];
    const float* bhh0  = (const float*)d_in[12];
    const float* Wih1  = (const float*)d_in[13];
    const float* Whh1  = (const float*)d_in[14];
    const float* bih1  = (const float*)d_in[15];
    const float* bhh1  = (const float*)d_in[16];
    const float* fc1w  = (const float*)d_in[17];
    const float* fc1b  = (const float*)d_in[18];
    const float* fc2w  = (const float*)d_in[19];
    const float* fc2b  = (const float*)d_in[20];
    const int*   tw    = (const int*)d_in[21];
    const int*   lens  = (const int*)d_in[22];

    float* ws = (float*)d_ws;
    float*          buf_gates = ws;                                   // gpre0
    unsigned short* x_bf      = (unsigned short*)(ws + 8388608);
    float*          buf_part  = ws + 8388608;                         // alias (4 slots)
    unsigned short* Wih0_bf   = (unsigned short*)(ws + 10485760);
    float*          buf_y1    = ws + 16384000;
    unsigned short* buf_hbf   = (unsigned short*)(ws + 18481152);
    int*            buf_flags = (int*)(ws + 18579456);
    float*          buf_hidden1 = ws + 18587904;
    unsigned short* fin_bf    = (unsigned short*)(ws + 22917376);
    unsigned short* fc1w_bf   = (unsigned short*)(ws + 25014528);
    unsigned short* fc1out_bf = (unsigned short*)(ws + 26063104);

    const size_t fold_end_bytes = (size_t)(27111680 + 8192000) * 4;
    const int cvtfc2 = (ws_size >= fold_end_bytes) ? 1 : 0;
    unsigned short* fc2w_bf = cvtfc2 ? (unsigned short*)(ws + 27111680)
                                     : (unsigned short*)ws;   // post-LSTM alias

    float* out   = (float*)d_out;
    float* out_hn  = out + Y_SZ;
    float* out_cn  = out + Y_SZ + HN_SZ;
    float* out_ctx = out + CTX_OFF;

    // 0. fused prep
    prep_kernel<<<3585, 256, 0, stream>>>(Wih0, Wih0_bf, fc1w, fc1w_bf,
                                          emb, ctxin, tw, x_bf, buf_flags);

    // 1. gates0_pre = x @ Wih0^T + bih0 + bhh0
    gemm_lds_bt<<<512, 256, 0, stream>>>(
        x_bf, Wih0_bf, bih0, bhh0, buf_gates, nullptr, 2048, 4096, 2048, 0, 0);

    // 2. Both LSTM layers + throttled nt D-group fc2w convert (grid 256)
    lstm_fused3<<<3 * LBLK + 64, 256, 0, stream>>>(
        buf_gates, Whh0, Wih1, Whh1, bih1, bhh1, h0, c0,
        buf_y1, fin_bf, out_hn, out_cn, buf_hbf, buf_part, buf_flags,
        fc2w, fc2w_bf, cvtfc2);

    // 3. fc2 weight convert fallback (only if workspace was too small)
    if (!cvtfc2)
        cvt_bf16_kernel<<<2048, 256, 0, stream>>>(fc2w, fc2w_bf, VOCAB * HID / 8);

    // 4. Attention: hidden1 (fp32 exact) then fused p/win+QK+softmax+PV
    gemm_bt<<<dim3(512 / 64, 2048 / 128), 256, 0, stream>>>(
        buf_y1, aw1, ab1, nullptr, buf_hidden1, 2048, 512, 1024, 2 /*tanh*/);
    attn_fused4<<<512, 256, 0, stream>>>(buf_y1, enc, buf_hidden1, aw2, ab2, lens,
                                         out_ctx, fin_bf);

    // 5. fc1 = relu([ctx, y1] @ fc1_w^T + fc1_b) -> bf16
    gemm_lds_bt<<<128, 256, 0, stream>>>(
        fin_bf, fc1w_bf, fc1b, nullptr, nullptr, fc1out_bf, 2048, 1024, 2048, 1, 0);

    // 6. fc2 -> fp32 d_out (nontemporal, coalesced via LDS transpose)
    gemm_lds_bt<<<4000, 256, 0, stream>>>(
        fc1out_bf, fc2w_bf, fc2b, nullptr, out, nullptr, 2048, VOCAB, 1024, 0, 1);
}